// Round 5
// baseline (555.822 us; speedup 1.0000x reference)
//
#include <hip/hip_runtime.h>
#include <hip/hip_bf16.h>
#include <math.h>

#define QLEN 1024
#define MLEN 1024
#define BSZ 4
#define KLEN 2048
#define NH 16
#define DH 64
#define DM 1024
#define DI 4096
#define NHD 1024
#define LN_EPS 1e-5f

typedef short bf16x8 __attribute__((ext_vector_type(8)));
typedef float f32x4 __attribute__((ext_vector_type(4)));
typedef unsigned int uint4v __attribute__((ext_vector_type(4)));

__device__ __forceinline__ float bf2f(unsigned short u) {
    union { unsigned u32; float f; } x; x.u32 = ((unsigned)u) << 16; return x.f;
}
__device__ __forceinline__ unsigned short f2bf(float f) {
    __hip_bfloat16 h = __float2bfloat16(f);
    return *(unsigned short*)&h;
}
// async global->LDS, 16B per lane (wave-uniform LDS base + lane*16 pattern)
__device__ __forceinline__ void gload16(const void* g, void* l) {
    __builtin_amdgcn_global_load_lds((const __attribute__((address_space(1))) unsigned int*)g,
                                     (__attribute__((address_space(3))) unsigned int*)l, 16, 0, 0);
}

// ---------------- workspace layout (BYTE offsets) ----------------
static const size_t OFF_CATB  = 0;           //  cat bf16 (dead after qkv gemm)
static const size_t OFF_VTG   = 0;           //  Vt_g bf16 [64 bn][64 d][2048 keys] (reuses CATB)
static const size_t OFF_WHB   = 16777216;    //  w_heads bf16 [8192][3072]
static const size_t OFF_RB    = 67108864;    //  r bf16 [2048][1024]
static const size_t OFF_RHKB  = 71303168;    //  r_head_k bf16 [2048][1024]
static const size_t OFF_AVB   = 75497472;    //  attn_vec bf16 [4096][1024]
static const size_t OFF_TMP   = 83886080;    //  tmp fp32 [4096][1024]
static const size_t OFF_LN1F  = 100663296;   //  ln1 fp32
static const size_t OFF_LN1B  = 117440512;   //  ln1 bf16
static const size_t OFF_FFHB  = 125829120;   //  ff_hid bf16 [4096][4096]
static const size_t OFF_QKVWT = 159383552;   //  qkv_w^T bf16 [3072][1024]
static const size_t OFF_RWT   = 165675008;   //  r_w^T bf16
static const size_t OFF_OWT   = 167772160;   //  o_w^T bf16
static const size_t OFF_FFW1T = 169869312;   //  ff_w1^T bf16
static const size_t OFF_FFW2T = 178257920;   //  ff_w2^T bf16
static const size_t OFF_BK    = 186646528;   //  bias_k fp32 [64 bn][2048]
static const size_t OFF_BR    = 187170816;   //  bias_r fp32 [16 n][2048]

// ---------------- casts ----------------
__global__ __launch_bounds__(256) void cast_cat(const float* __restrict__ mems,
                                                const float* __restrict__ dec,
                                                unsigned short* __restrict__ out) {
    size_t i8 = ((size_t)blockIdx.x * 256 + threadIdx.x) * 8;
    const size_t half = (size_t)MLEN * BSZ * DM;
    const float* src = (i8 < half) ? (mems + i8) : (dec + (i8 - half));
    float4 v0 = *(const float4*)src;
    float4 v1 = *(const float4*)(src + 4);
    ushort4 o0 = {f2bf(v0.x), f2bf(v0.y), f2bf(v0.z), f2bf(v0.w)};
    ushort4 o1 = {f2bf(v1.x), f2bf(v1.y), f2bf(v1.z), f2bf(v1.w)};
    *(ushort4*)&out[i8] = o0;
    *(ushort4*)&out[i8 + 4] = o1;
}

__global__ __launch_bounds__(256) void cast_f32_bf16(const float* __restrict__ in,
                                                     unsigned short* __restrict__ out) {
    size_t i8 = ((size_t)blockIdx.x * 256 + threadIdx.x) * 8;
    float4 v0 = *(const float4*)(in + i8);
    float4 v1 = *(const float4*)(in + i8 + 4);
    ushort4 o0 = {f2bf(v0.x), f2bf(v0.y), f2bf(v0.z), f2bf(v0.w)};
    ushort4 o1 = {f2bf(v1.x), f2bf(v1.y), f2bf(v1.z), f2bf(v1.w)};
    *(ushort4*)&out[i8] = o0;
    *(ushort4*)&out[i8 + 4] = o1;
}

// in [K][N] fp32 -> out [N][K] bf16
__global__ __launch_bounds__(256) void transpose_cast(const float* __restrict__ in,
                                                      unsigned short* __restrict__ out,
                                                      int K, int N) {
    __shared__ float tile[32][33];
    const int t = threadIdx.x;
    const int n0 = blockIdx.x * 32;
    const int k0 = blockIdx.y * 32;
    const int r = t >> 3;
    const int c0 = (t & 7) << 2;
    float4 v = *(const float4*)&in[(size_t)(k0 + r) * N + n0 + c0];
    tile[r][c0 + 0] = v.x; tile[r][c0 + 1] = v.y;
    tile[r][c0 + 2] = v.z; tile[r][c0 + 3] = v.w;
    __syncthreads();
    ushort4 o = {f2bf(tile[c0 + 0][r]), f2bf(tile[c0 + 1][r]),
                 f2bf(tile[c0 + 2][r]), f2bf(tile[c0 + 3][r])};
    *(ushort4*)&out[(size_t)(n0 + r) * K + k0 + c0] = o;
}

// ---------------- bf16 MFMA GEMM, m97-style: global_load_lds + linear LDS ----------------
// C[M,N] = A[M,K] @ Bt[N,K]^T. flags: 1=+bias, 2=relu, 4=bf16 out (else fp32)
__global__ __launch_bounds__(256) void gemm_bf16(const unsigned short* __restrict__ A,
                                                 const unsigned short* __restrict__ Bt,
                                                 const float* __restrict__ bias,
                                                 void* __restrict__ C,
                                                 int M, int N, int K, int flags) {
    __shared__ __align__(16) unsigned short As[128 * 64];
    __shared__ __align__(16) unsigned short Bs[128 * 64];

    const int tid = threadIdx.x;
    const int w = tid >> 6, l = tid & 63;
    const int wr = w >> 1, wc = w & 1;
    const int row0 = blockIdx.y * 128;
    const int col0 = blockIdx.x * 128;
    const int r32 = tid >> 3;      // 0..31
    const int c8 = tid & 7;        // 0..7

    f32x4 acc[4][4] = {};

    const int nt = K >> 6;
    for (int kt = 0; kt < nt; ++kt) {
        const int k0 = kt << 6;
        __syncthreads();  // all waves done reading previous tile
#pragma unroll
        for (int q = 0; q < 4; ++q) {
            const int row = q * 32 + r32;
            gload16(&A[(size_t)(row0 + row) * K + k0 + c8 * 8], &As[row * 64 + c8 * 8]);
            gload16(&Bt[(size_t)(col0 + row) * K + k0 + c8 * 8], &Bs[row * 64 + c8 * 8]);
        }
        __syncthreads();  // compiler drains vmcnt(0) before barrier -> LDS ready
#pragma unroll
        for (int ks = 0; ks < 2; ++ks) {
            bf16x8 a[4], bfr[4];
#pragma unroll
            for (int m = 0; m < 4; ++m) {
                const int arow = wr * 64 + m * 16 + (l & 15);
                a[m] = *(const bf16x8*)&As[arow * 64 + ks * 32 + (l >> 4) * 8];
            }
#pragma unroll
            for (int n = 0; n < 4; ++n) {
                const int brow = wc * 64 + n * 16 + (l & 15);
                bfr[n] = *(const bf16x8*)&Bs[brow * 64 + ks * 32 + (l >> 4) * 8];
            }
#pragma unroll
            for (int m = 0; m < 4; ++m)
#pragma unroll
                for (int n = 0; n < 4; ++n)
                    acc[m][n] = __builtin_amdgcn_mfma_f32_16x16x32_bf16(a[m], bfr[n], acc[m][n], 0, 0, 0);
        }
    }

#pragma unroll
    for (int n = 0; n < 4; ++n) {
        const int ccol = col0 + wc * 64 + n * 16 + (l & 15);
        const float bv = (flags & 1) ? bias[ccol] : 0.0f;
#pragma unroll
        for (int m = 0; m < 4; ++m) {
            const int crow0 = row0 + wr * 64 + m * 16 + ((l >> 4) << 2);
#pragma unroll
            for (int reg = 0; reg < 4; ++reg) {
                float v = acc[m][n][reg] + bv;
                if (flags & 2) v = fmaxf(v, 0.0f);
                if (flags & 4)
                    ((unsigned short*)C)[(size_t)(crow0 + reg) * N + ccol] = f2bf(v);
                else
                    ((float*)C)[(size_t)(crow0 + reg) * N + ccol] = v;
            }
        }
    }
}

// ---------------- V transpose to global: Vt_g[bn][d][key] ----------------
__global__ __launch_bounds__(256) void vtrans(const unsigned short* __restrict__ whb,
                                              unsigned short* __restrict__ vtg) {
    __shared__ unsigned short tile[64][72];
    const int bn = blockIdx.y;
    const int b = bn >> 4, n = bn & 15, nb = n * 64;
    const int jt0 = blockIdx.x * 64;
    const int tid = threadIdx.x;
#pragma unroll
    for (int g = 0; g < 2; ++g) {
        int f = g * 256 + tid;
        int key = f >> 3, c = f & 7;
        uint4v v = *(const uint4v*)&whb[((size_t)(jt0 + key) * 4 + b) * 3072 + 2048 + nb + c * 8];
        *(uint4v*)&tile[key][c * 8] = v;
    }
    __syncthreads();
#pragma unroll
    for (int g = 0; g < 2; ++g) {
        int f = g * 256 + tid;
        int d = f >> 3, ck = f & 7;
        unsigned short tmp[8];
#pragma unroll
        for (int e = 0; e < 8; ++e) tmp[e] = tile[ck * 8 + e][d];
        *(uint4v*)&vtg[(size_t)bn * 131072 + (size_t)d * 2048 + jt0 + ck * 8] = *(uint4v*)tmp;
    }
}

// ---------------- rank-1 bias precompute ----------------
__global__ __launch_bounds__(256) void bias_kernel(const unsigned short* __restrict__ whb,
                                                   const unsigned short* __restrict__ rhkb,
                                                   const float* __restrict__ r_w_bias,
                                                   const float* __restrict__ r_r_bias,
                                                   float* __restrict__ bias_k,
                                                   float* __restrict__ bias_r) {
    int id = blockIdx.x * 256 + threadIdx.x;
    if (id < 64 * 2048) {
        int bn = id >> 11, j = id & 2047;
        int b = bn >> 4, n = bn & 15;
        const unsigned short* kp = &whb[((size_t)j * 4 + b) * 3072 + 1024 + n * 64];
        const float* wb = &r_w_bias[n * 64];
        float acc = 0.f;
#pragma unroll
        for (int d = 0; d < 64; ++d) acc += wb[d] * bf2f(kp[d]);
        bias_k[id] = acc;
    } else {
        int id2 = id - 64 * 2048;
        if (id2 < 16 * 2048) {
            int n = id2 >> 11, rel = id2 & 2047;
            const unsigned short* rp = &rhkb[(size_t)rel * 1024 + n * 64];
            const float* rb = &r_r_bias[n * 64];
            float acc = 0.f;
#pragma unroll
            for (int d = 0; d < 64; ++d) acc += rb[d] * bf2f(rp[d]);
            bias_r[id2] = acc;
        }
    }
}

// ---------------- MFMA flash attention (reg-prefetch, bf16 BD band, 3 blocks/CU) --------
__global__ __launch_bounds__(256) void flash_attn_mfma(const unsigned short* __restrict__ whb,
                                                       const unsigned short* __restrict__ rhkb,
                                                       const unsigned short* __restrict__ vtg,
                                                       const float* __restrict__ bias_k,
                                                       const float* __restrict__ bias_r,
                                                       unsigned short* __restrict__ avb) {
    const int bx = blockIdx.x;
    const int bn = blockIdx.y;
    const int b = bn >> 4, n = bn & 15, nb = n * 64;
    const int i0 = bx << 6;
    const int tid = threadIdx.x;
    const int wq = tid >> 6;
    const int lane = tid & 63;
    const int rg = lane >> 4;
    const int lc = lane & 15;

    __shared__ __align__(16) unsigned short Ks[4096];    // [key][64d] swizzled
    __shared__ __align__(16) unsigned short Rs[8192];    // 2 circular slots [64][64d] swizzled
    __shared__ __align__(16) unsigned short Vt[4096];    // [d][64key] swizzled
    __shared__ __align__(16) unsigned short Ps[4096];    // per-wave [16 q][64 key] swizzled
    __shared__ __align__(16) unsigned short BDt[4][80 * 20]; // per-wave [band 80][q, pitch 20] bf16 (incl bias_r)

    // persistent Q fragments
    bf16x8 qf[2];
    {
        const int qrow = MLEN + i0 + wq * 16 + lc;
        const unsigned short* qp = whb + ((size_t)qrow * 4 + b) * 3072 + nb + rg * 8;
        qf[0] = *(const bf16x8*)(qp);
        qf[1] = *(const bf16x8*)(qp + 32);
    }

    f32x4 Oacc[4] = {};
    float mrun[4] = {-INFINITY, -INFINITY, -INFINITY, -INFINITY};
    float lrun[4] = {0.f, 0.f, 0.f, 0.f};

    const int ntiles = bx + 17;

    // ---- prologue: prefetch tile 0 into registers ----
    uint4v pk[2], pv[2], pr[4];
    {
#pragma unroll
        for (int g = 0; g < 2; ++g) {
            const int f = g * 256 + tid;
            const int row = f >> 3, c = f & 7;
            pk[g] = *(const uint4v*)&whb[((size_t)row * 4 + b) * 3072 + 1024 + nb + c * 8];
            pv[g] = *(const uint4v*)&vtg[(size_t)bn * 131072 + (size_t)row * 2048 + c * 8];
        }
        const int relbase0 = 960 - i0;  // >= 0 for bx <= 15
#pragma unroll
        for (int g2 = 0; g2 < 4; ++g2) {
            const int row = g2 * 32 + (tid >> 3);
            const int c = tid & 7;
            int a = relbase0 + row;
            if (a > 2047) a = 2047;
            pr[g2] = *(const uint4v*)&rhkb[(size_t)a * 1024 + nb + c * 8];
        }
    }

    for (int kt = 0; kt < ntiles; ++kt) {
        const int jt0 = kt << 6;
        const int relbase = jt0 - i0 + 960;
        __syncthreads();  // previous compute done reading LDS

        // ---- write prefetched regs -> LDS ----
#pragma unroll
        for (int g = 0; g < 2; ++g) {
            const int f = g * 256 + tid;
            const int row = f >> 3, c = f & 7;
            *(uint4v*)&Ks[row * 64 + ((c ^ (row & 7)) << 3)] = pk[g];
            *(uint4v*)&Vt[row * 64 + ((c ^ (row & 7)) << 3)] = pv[g];
        }
        if (kt == 0) {
#pragma unroll
            for (int g2 = 0; g2 < 4; ++g2) {
                const int row = g2 * 32 + (tid >> 3);
                const int c = tid & 7;
                const int a = relbase + row;
                const int dst = ((a >> 6) & 1) * 4096 + (a & 63) * 64 + ((c ^ (a & 7)) << 3);
                *(uint4v*)&Rs[dst] = pr[g2];
            }
        } else {
#pragma unroll
            for (int g2 = 0; g2 < 2; ++g2) {
                const int row = 64 + g2 * 32 + (tid >> 3);
                const int c = tid & 7;
                const int a = relbase + row;
                const int dst = ((a >> 6) & 1) * 4096 + (a & 63) * 64 + ((c ^ (a & 7)) << 3);
                *(uint4v*)&Rs[dst] = pr[g2];
            }
        }
        // ---- issue next-tile prefetch into regs (written to LDS next iter) ----
        if (kt + 1 < ntiles) {
            const int jn = jt0 + 64;
#pragma unroll
            for (int g = 0; g < 2; ++g) {
                const int f = g * 256 + tid;
                const int row = f >> 3, c = f & 7;
                pk[g] = *(const uint4v*)&whb[((size_t)(jn + row) * 4 + b) * 3072 + 1024 + nb + c * 8];
                pv[g] = *(const uint4v*)&vtg[(size_t)bn * 131072 + (size_t)row * 2048 + jn + c * 8];
            }
            const int rbn = relbase + 64;
#pragma unroll
            for (int g2 = 0; g2 < 2; ++g2) {
                const int row = 64 + g2 * 32 + (tid >> 3);
                const int c = tid & 7;
                int a = rbn + row;
                if (a > 2047) a = 2047;
                pr[g2] = *(const uint4v*)&rhkb[(size_t)a * 1024 + nb + c * 8];
            }
        }
        __syncthreads();  // LDS tiles ready

        // ---- AC = Q.K^T ----
        f32x4 Sacc[4];
#pragma unroll
        for (int nf = 0; nf < 4; ++nf) {
            const int key = nf * 16 + lc;
            const int c7 = key & 7;
            const bf16x8 kf0 = *(const bf16x8*)&Ks[key * 64 + ((rg ^ c7) << 3)];
            const bf16x8 kf1 = *(const bf16x8*)&Ks[key * 64 + (((4 + rg) ^ c7) << 3)];
            f32x4 z = {0.f, 0.f, 0.f, 0.f};
            z = __builtin_amdgcn_mfma_f32_16x16x32_bf16(qf[0], kf0, z, 0, 0, 0);
            Sacc[nf] = __builtin_amdgcn_mfma_f32_16x16x32_bf16(qf[1], kf1, z, 0, 0, 0);
        }

        // ---- BD band = Q.Rwin^T + bias_r, bf16 transposed store ----
        unsigned short* bdt = &BDt[wq][0];
        const int nflo = 3 - wq;
#pragma unroll
        for (int e5 = 0; e5 < 5; ++e5) {
            const int nf8 = nflo + e5;
            const int a = relbase + nf8 * 16 + lc;
            const int rbase = ((a >> 6) & 1) * 4096 + (a & 63) * 64;
            const int c7 = a & 7;
            const bf16x8 rf0 = *(const bf16x8*)&Rs[rbase + ((rg ^ c7) << 3)];
            const bf16x8 rf1 = *(const bf16x8*)&Rs[rbase + (((4 + rg) ^ c7) << 3)];
            f32x4 bd = {0.f, 0.f, 0.f, 0.f};
            bd = __builtin_amdgcn_mfma_f32_16x16x32_bf16(qf[0], rf0, bd, 0, 0, 0);
            bd = __builtin_amdgcn_mfma_f32_16x16x32_bf16(qf[1], rf1, bd, 0, 0, 0);
            const int aa = a > 2047 ? 2047 : a;
            const float brv = bias_r[n * 2048 + aa];
            const int bb = e5 * 16 + lc;  // band offset in [0,80)
            ushort4 p4 = {f2bf(bd[0] + brv), f2bf(bd[1] + brv),
                          f2bf(bd[2] + brv), f2bf(bd[3] + brv)};
            *(ushort4*)&bdt[bb * 20 + rg * 4] = p4;
        }

        // ---- scores + online softmax ----
        float sv[4][4];
        float tmax[4] = {-INFINITY, -INFINITY, -INFINITY, -INFINITY};
#pragma unroll
        for (int nf = 0; nf < 4; ++nf) {
            const int jl = nf * 16 + lc;
            const float bkv = bias_k[(size_t)bn * 2048 + jt0 + jl];
#pragma unroll
            for (int r = 0; r < 4; ++r) {
                const int qr = rg * 4 + r;
                const int bb = 15 + jl - qr;           // band offset (wq-independent)
                const int a = relbase + 48 + jl - qr;  // rel index j-i+1023 ... = relbase + o, o = bb + (3-wq)*16 - 16wq? no: o = 63+jl-wq*16-qr
                float s = Sacc[nf][r] + bkv + bf2f(bdt[bb * 20 + qr]);
                const int o = 63 + jl - wq * 16 - qr;
                s = (relbase + o <= 2047) ? s * 0.125f : -INFINITY;
                sv[nf][r] = s;
                tmax[r] = fmaxf(tmax[r], s);
                (void)a;
            }
        }
        float ef[4];
#pragma unroll
        for (int r = 0; r < 4; ++r) {
            float tm = tmax[r];
            tm = fmaxf(tm, __shfl_xor(tm, 1));
            tm = fmaxf(tm, __shfl_xor(tm, 2));
            tm = fmaxf(tm, __shfl_xor(tm, 4));
            tm = fmaxf(tm, __shfl_xor(tm, 8));
            const float mn = fmaxf(mrun[r], tm);
            ef[r] = __expf(mrun[r] - mn);
            mrun[r] = mn;
        }
        float rsum[4] = {0.f, 0.f, 0.f, 0.f};
#pragma unroll
        for (int nf = 0; nf < 4; ++nf) {
            const int jl = nf * 16 + lc;
#pragma unroll
            for (int r = 0; r < 4; ++r) {
                const int qr = rg * 4 + r;
                const float p = __expf(sv[nf][r] - mrun[r]);
                rsum[r] += p;
                Ps[wq * 1024 + qr * 64 + (((jl >> 3) ^ (qr & 7)) << 3) + (jl & 7)] = f2bf(p);
            }
        }
#pragma unroll
        for (int r = 0; r < 4; ++r) {
            float rs = rsum[r];
            rs += __shfl_xor(rs, 1);
            rs += __shfl_xor(rs, 2);
            rs += __shfl_xor(rs, 4);
            rs += __shfl_xor(rs, 8);
            lrun[r] = lrun[r] * ef[r] + rs;
        }
#pragma unroll
        for (int nf = 0; nf < 4; ++nf)
#pragma unroll
            for (int r = 0; r < 4; ++r) Oacc[nf][r] *= ef[r];

        // ---- PV ----
        {
            const int c7 = lc & 7;
            const bf16x8 pf0 = *(const bf16x8*)&Ps[wq * 1024 + lc * 64 + ((rg ^ c7) << 3)];
            const bf16x8 pf1 = *(const bf16x8*)&Ps[wq * 1024 + lc * 64 + (((4 + rg) ^ c7) << 3)];
#pragma unroll
            for (int nf = 0; nf < 4; ++nf) {
                const int d = nf * 16 + lc;
                const int d7 = d & 7;
                const bf16x8 vf0 = *(const bf16x8*)&Vt[d * 64 + ((rg ^ d7) << 3)];
                const bf16x8 vf1 = *(const bf16x8*)&Vt[d * 64 + (((4 + rg) ^ d7) << 3)];
                Oacc[nf] = __builtin_amdgcn_mfma_f32_16x16x32_bf16(pf0, vf0, Oacc[nf], 0, 0, 0);
                Oacc[nf] = __builtin_amdgcn_mfma_f32_16x16x32_bf16(pf1, vf1, Oacc[nf], 0, 0, 0);
            }
        }
    }

    // ---- epilogue ----
    float inv[4];
#pragma unroll
    for (int r = 0; r < 4; ++r) inv[r] = 1.0f / lrun[r];
#pragma unroll
    for (int nf = 0; nf < 4; ++nf) {
        const int d = nf * 16 + lc;
#pragma unroll
        for (int r = 0; r < 4; ++r) {
            const int iq = i0 + wq * 16 + rg * 4 + r;
            avb[((size_t)iq * 4 + b) * 1024 + nb + d] = f2bf(Oacc[nf][r] * inv[r]);
        }
    }
}

// ---------------- residual add + layernorm ----------------
__global__ __launch_bounds__(256) void add_ln_kernel(const float* __restrict__ a,
                                                     const float* __restrict__ b,
                                                     const float* __restrict__ w,
                                                     const float* __restrict__ bias,
                                                     float* __restrict__ out,
                                                     unsigned short* __restrict__ out_bf) {
    const int row = blockIdx.x;
    const int t = threadIdx.x;
    __shared__ float xs[DM];
    __shared__ float red[256];

    const float* ar = a + (size_t)row * DM;
    const float* br = b + (size_t)row * DM;

    float lsum = 0.f;
#pragma unroll
    for (int c = t; c < DM; c += 256) {
        float v = ar[c] + br[c];
        xs[c] = v;
        lsum += v;
    }
    red[t] = lsum;
    __syncthreads();
    for (int off = 128; off > 0; off >>= 1) {
        if (t < off) red[t] += red[t + off];
        __syncthreads();
    }
    const float mu = red[0] * (1.0f / DM);
    __syncthreads();

    float lvar = 0.f;
#pragma unroll
    for (int c = t; c < DM; c += 256) {
        float dv = xs[c] - mu;
        lvar += dv * dv;
    }
    red[t] = lvar;
    __syncthreads();
    for (int off = 128; off > 0; off >>= 1) {
        if (t < off) red[t] += red[t + off];
        __syncthreads();
    }
    const float rstd = rsqrtf(red[0] * (1.0f / DM) + LN_EPS);
    __syncthreads();

    float* orow = out + (size_t)row * DM;
#pragma unroll
    for (int c = t; c < DM; c += 256) {
        float v = (xs[c] - mu) * rstd * w[c] + bias[c];
        orow[c] = v;
        if (out_bf) out_bf[(size_t)row * DM + c] = f2bf(v);
    }
}

extern "C" void kernel_launch(void* const* d_in, const int* in_sizes, int n_in,
                              void* d_out, int out_size, void* d_ws, size_t ws_size,
                              hipStream_t stream) {
    const float* dec_inp  = (const float*)d_in[0];
    const float* r        = (const float*)d_in[1];
    const float* r_w_bias = (const float*)d_in[2];
    const float* r_r_bias = (const float*)d_in[3];
    const float* mems     = (const float*)d_in[4];
    const float* qkv_w    = (const float*)d_in[6];
    const float* r_w      = (const float*)d_in[7];
    const float* o_w      = (const float*)d_in[8];
    const float* ln1_w    = (const float*)d_in[9];
    const float* ln1_b    = (const float*)d_in[10];
    const float* ln2_w    = (const float*)d_in[11];
    const float* ln2_b    = (const float*)d_in[12];
    const float* ff_w1    = (const float*)d_in[13];
    const float* ff_b1    = (const float*)d_in[14];
    const float* ff_w2    = (const float*)d_in[15];
    const float* ff_b2    = (const float*)d_in[16];
    float* out = (float*)d_out;
    char* ws = (char*)d_ws;

    unsigned short* catb  = (unsigned short*)(ws + OFF_CATB);
    unsigned short* vtg   = (unsigned short*)(ws + OFF_VTG);
    unsigned short* whb   = (unsigned short*)(ws + OFF_WHB);
    unsigned short* rb    = (unsigned short*)(ws + OFF_RB);
    unsigned short* rhkb  = (unsigned short*)(ws + OFF_RHKB);
    unsigned short* avb   = (unsigned short*)(ws + OFF_AVB);
    float*          tmp   = (float*)(ws + OFF_TMP);
    float*          ln1f  = (float*)(ws + OFF_LN1F);
    unsigned short* ln1b  = (unsigned short*)(ws + OFF_LN1B);
    unsigned short* ffhb  = (unsigned short*)(ws + OFF_FFHB);
    unsigned short* qkvwT = (unsigned short*)(ws + OFF_QKVWT);
    unsigned short* rwT   = (unsigned short*)(ws + OFF_RWT);
    unsigned short* owT   = (unsigned short*)(ws + OFF_OWT);
    unsigned short* ffw1T = (unsigned short*)(ws + OFF_FFW1T);
    unsigned short* ffw2T = (unsigned short*)(ws + OFF_FFW2T);
    float*          bk    = (float*)(ws + OFF_BK);
    float*          brr   = (float*)(ws + OFF_BR);

    // casts & weight transposes
    cast_cat<<<dim3(4096), 256, 0, stream>>>(mems, dec_inp, catb);
    cast_f32_bf16<<<dim3(1024), 256, 0, stream>>>(r, rb);
    transpose_cast<<<dim3(96, 32), 256, 0, stream>>>(qkv_w, qkvwT, 1024, 3072);
    transpose_cast<<<dim3(32, 32), 256, 0, stream>>>(r_w, rwT, 1024, 1024);
    transpose_cast<<<dim3(32, 32), 256, 0, stream>>>(o_w, owT, 1024, 1024);
    transpose_cast<<<dim3(128, 32), 256, 0, stream>>>(ff_w1, ffw1T, 1024, 4096);
    transpose_cast<<<dim3(32, 128), 256, 0, stream>>>(ff_w2, ffw2T, 4096, 1024);

    // projections
    gemm_bf16<<<dim3(24, 64), 256, 0, stream>>>(catb, qkvwT, nullptr, whb,
                                                KLEN * BSZ, 3 * NHD, DM, 4);
    gemm_bf16<<<dim3(8, 16), 256, 0, stream>>>(rb, rwT, nullptr, rhkb,
                                               KLEN, NHD, DM, 4);

    // attention precomputes (catb dead now; vtg reuses it)
    vtrans<<<dim3(32, 64), 256, 0, stream>>>(whb, vtg);
    bias_kernel<<<dim3(640), 256, 0, stream>>>(whb, rhkb, r_w_bias, r_r_bias, bk, brr);

    // MFMA flash attention
    flash_attn_mfma<<<dim3(QLEN / 64, BSZ * NH), 256, 0, stream>>>(
        whb, rhkb, vtg, bk, brr, avb);

    // output projection + LN + FFN + LN
    gemm_bf16<<<dim3(8, 32), 256, 0, stream>>>(avb, owT, nullptr, tmp,
                                               QLEN * BSZ, DM, NHD, 0);
    add_ln_kernel<<<dim3(QLEN * BSZ), 256, 0, stream>>>(
        dec_inp, tmp, ln1_w, ln1_b, ln1f, ln1b);
    gemm_bf16<<<dim3(32, 32), 256, 0, stream>>>(ln1b, ffw1T, ff_b1, ffhb,
                                                QLEN * BSZ, DI, DM, 1 | 2 | 4);
    gemm_bf16<<<dim3(8, 32), 256, 0, stream>>>(ffhb, ffw2T, ff_b2, tmp,
                                               QLEN * BSZ, DM, DI, 1);
    add_ln_kernel<<<dim3(QLEN * BSZ), 256, 0, stream>>>(
        ln1f, tmp, ln2_w, ln2_b, out, nullptr);
}

// Round 6
// 470.450 us; speedup vs baseline: 1.1815x; 1.1815x over previous
//
#include <hip/hip_runtime.h>
#include <hip/hip_bf16.h>
#include <math.h>

#define QLEN 1024
#define MLEN 1024
#define BSZ 4
#define KLEN 2048
#define NH 16
#define DH 64
#define DM 1024
#define DI 4096
#define NHD 1024
#define LN_EPS 1e-5f

typedef short bf16x8 __attribute__((ext_vector_type(8)));
typedef float f32x4 __attribute__((ext_vector_type(4)));
typedef unsigned int uint4v __attribute__((ext_vector_type(4)));

__device__ __forceinline__ float bf2f(unsigned short u) {
    union { unsigned u32; float f; } x; x.u32 = ((unsigned)u) << 16; return x.f;
}
__device__ __forceinline__ unsigned short f2bf(float f) {
    __hip_bfloat16 h = __float2bfloat16(f);
    return *(unsigned short*)&h;
}

// ---------------- workspace layout (BYTE offsets) ----------------
static const size_t OFF_CATB  = 0;           //  cat bf16 (dead after qkv gemm)
static const size_t OFF_VTG   = 0;           //  Vt_g bf16 [64 bn][64 d][2048 keys] (reuses CATB)
static const size_t OFF_WHB   = 16777216;    //  w_heads bf16 [8192][3072]
static const size_t OFF_RB    = 67108864;    //  r bf16 [2048][1024]
static const size_t OFF_RHKB  = 71303168;    //  r_head_k bf16 [2048][1024]
static const size_t OFF_AVB   = 75497472;    //  attn_vec bf16 [4096][1024]
static const size_t OFF_TMP   = 83886080;    //  tmp fp32 [4096][1024]
static const size_t OFF_LN1F  = 100663296;   //  ln1 fp32
static const size_t OFF_LN1B  = 117440512;   //  ln1 bf16
static const size_t OFF_FFHB  = 125829120;   //  ff_hid bf16 [4096][4096]
static const size_t OFF_QKVWT = 159383552;   //  qkv_w^T bf16 [3072][1024]
static const size_t OFF_RWT   = 165675008;   //  r_w^T bf16
static const size_t OFF_OWT   = 167772160;   //  o_w^T bf16
static const size_t OFF_FFW1T = 169869312;   //  ff_w1^T bf16
static const size_t OFF_FFW2T = 178257920;   //  ff_w2^T bf16
static const size_t OFF_BK    = 186646528;   //  bias_k fp32 [64 bn][2048]
static const size_t OFF_BR    = 187170816;   //  bias_r fp32 [16 n][2048]

// ---------------- casts ----------------
__global__ __launch_bounds__(256) void cast_cat(const float* __restrict__ mems,
                                                const float* __restrict__ dec,
                                                unsigned short* __restrict__ out) {
    size_t i8 = ((size_t)blockIdx.x * 256 + threadIdx.x) * 8;
    const size_t half = (size_t)MLEN * BSZ * DM;
    const float* src = (i8 < half) ? (mems + i8) : (dec + (i8 - half));
    float4 v0 = *(const float4*)src;
    float4 v1 = *(const float4*)(src + 4);
    ushort4 o0 = {f2bf(v0.x), f2bf(v0.y), f2bf(v0.z), f2bf(v0.w)};
    ushort4 o1 = {f2bf(v1.x), f2bf(v1.y), f2bf(v1.z), f2bf(v1.w)};
    *(ushort4*)&out[i8] = o0;
    *(ushort4*)&out[i8 + 4] = o1;
}

__global__ __launch_bounds__(256) void cast_f32_bf16(const float* __restrict__ in,
                                                     unsigned short* __restrict__ out) {
    size_t i8 = ((size_t)blockIdx.x * 256 + threadIdx.x) * 8;
    float4 v0 = *(const float4*)(in + i8);
    float4 v1 = *(const float4*)(in + i8 + 4);
    ushort4 o0 = {f2bf(v0.x), f2bf(v0.y), f2bf(v0.z), f2bf(v0.w)};
    ushort4 o1 = {f2bf(v1.x), f2bf(v1.y), f2bf(v1.z), f2bf(v1.w)};
    *(ushort4*)&out[i8] = o0;
    *(ushort4*)&out[i8 + 4] = o1;
}

// in [K][N] fp32 -> out [N][K] bf16
__global__ __launch_bounds__(256) void transpose_cast(const float* __restrict__ in,
                                                      unsigned short* __restrict__ out,
                                                      int K, int N) {
    __shared__ float tile[32][33];
    const int t = threadIdx.x;
    const int n0 = blockIdx.x * 32;
    const int k0 = blockIdx.y * 32;
    const int r = t >> 3;
    const int c0 = (t & 7) << 2;
    float4 v = *(const float4*)&in[(size_t)(k0 + r) * N + n0 + c0];
    tile[r][c0 + 0] = v.x; tile[r][c0 + 1] = v.y;
    tile[r][c0 + 2] = v.z; tile[r][c0 + 3] = v.w;
    __syncthreads();
    ushort4 o = {f2bf(tile[c0 + 0][r]), f2bf(tile[c0 + 1][r]),
                 f2bf(tile[c0 + 2][r]), f2bf(tile[c0 + 3][r])};
    *(ushort4*)&out[(size_t)(n0 + r) * K + k0 + c0] = o;
}

// ---------------- bf16 MFMA GEMM (round-3/4 proven: reg-staged dbuf + XOR swizzle) ------
__global__ __launch_bounds__(256) void gemm_bf16(const unsigned short* __restrict__ A,
                                                 const unsigned short* __restrict__ Bt,
                                                 const float* __restrict__ bias,
                                                 void* __restrict__ C,
                                                 int M, int N, int K, int flags) {
    __shared__ __align__(16) unsigned short As[128 * 64];
    __shared__ __align__(16) unsigned short Bs[128 * 64];

    const int tid = threadIdx.x;
    const int w = tid >> 6, l = tid & 63;
    const int wr = w >> 1, wc = w & 1;
    const int row0 = blockIdx.y * 128;
    const int col0 = blockIdx.x * 128;

    f32x4 acc[4][4] = {};

    uint4v ra[4], rb[4];
    {
#pragma unroll
        for (int q = 0; q < 4; ++q) {
            int f = q * 256 + tid, r = f >> 3, c = f & 7;
            ra[q] = *(const uint4v*)&A[(size_t)(row0 + r) * K + c * 8];
            rb[q] = *(const uint4v*)&Bt[(size_t)(col0 + r) * K + c * 8];
        }
    }

    const int nt = K >> 6;
    for (int kt = 0; kt < nt; ++kt) {
        __syncthreads();
#pragma unroll
        for (int q = 0; q < 4; ++q) {
            int f = q * 256 + tid, r = f >> 3, c = f & 7;
            int sw = (c ^ (r & 7)) << 3;
            *(uint4v*)&As[r * 64 + sw] = ra[q];
            *(uint4v*)&Bs[r * 64 + sw] = rb[q];
        }
        __syncthreads();
        if (kt + 1 < nt) {
            const int k0 = (kt + 1) << 6;
#pragma unroll
            for (int q = 0; q < 4; ++q) {
                int f = q * 256 + tid, r = f >> 3, c = f & 7;
                ra[q] = *(const uint4v*)&A[(size_t)(row0 + r) * K + k0 + c * 8];
                rb[q] = *(const uint4v*)&Bt[(size_t)(col0 + r) * K + k0 + c * 8];
            }
        }
#pragma unroll
        for (int ks = 0; ks < 2; ++ks) {
            bf16x8 a[4], bfr[4];
#pragma unroll
            for (int m = 0; m < 4; ++m) {
                int arow = wr * 64 + m * 16 + (l & 15);
                int chunk = (ks * 4 + (l >> 4)) ^ (arow & 7);
                a[m] = *(const bf16x8*)&As[arow * 64 + chunk * 8];
            }
#pragma unroll
            for (int n = 0; n < 4; ++n) {
                int brow = wc * 64 + n * 16 + (l & 15);
                int chunk = (ks * 4 + (l >> 4)) ^ (brow & 7);
                bfr[n] = *(const bf16x8*)&Bs[brow * 64 + chunk * 8];
            }
#pragma unroll
            for (int m = 0; m < 4; ++m)
#pragma unroll
                for (int n = 0; n < 4; ++n)
                    acc[m][n] = __builtin_amdgcn_mfma_f32_16x16x32_bf16(a[m], bfr[n], acc[m][n], 0, 0, 0);
        }
    }

#pragma unroll
    for (int n = 0; n < 4; ++n) {
        const int ccol = col0 + wc * 64 + n * 16 + (l & 15);
        const float bv = (flags & 1) ? bias[ccol] : 0.0f;
#pragma unroll
        for (int m = 0; m < 4; ++m) {
            const int crow0 = row0 + wr * 64 + m * 16 + ((l >> 4) << 2);
#pragma unroll
            for (int reg = 0; reg < 4; ++reg) {
                float v = acc[m][n][reg] + bv;
                if (flags & 2) v = fmaxf(v, 0.0f);
                if (flags & 4)
                    ((unsigned short*)C)[(size_t)(crow0 + reg) * N + ccol] = f2bf(v);
                else
                    ((float*)C)[(size_t)(crow0 + reg) * N + ccol] = v;
            }
        }
    }
}

// ---------------- V transpose to global: Vt_g[bn][d][key] ----------------
__global__ __launch_bounds__(256) void vtrans(const unsigned short* __restrict__ whb,
                                              unsigned short* __restrict__ vtg) {
    __shared__ unsigned short tile[64][72];
    const int bn = blockIdx.y;
    const int b = bn >> 4, n = bn & 15, nb = n * 64;
    const int jt0 = blockIdx.x * 64;
    const int tid = threadIdx.x;
#pragma unroll
    for (int g = 0; g < 2; ++g) {
        int f = g * 256 + tid;
        int key = f >> 3, c = f & 7;
        uint4v v = *(const uint4v*)&whb[((size_t)(jt0 + key) * 4 + b) * 3072 + 2048 + nb + c * 8];
        *(uint4v*)&tile[key][c * 8] = v;
    }
    __syncthreads();
#pragma unroll
    for (int g = 0; g < 2; ++g) {
        int f = g * 256 + tid;
        int d = f >> 3, ck = f & 7;
        unsigned short tmp[8];
#pragma unroll
        for (int e = 0; e < 8; ++e) tmp[e] = tile[ck * 8 + e][d];
        *(uint4v*)&vtg[(size_t)bn * 131072 + (size_t)d * 2048 + jt0 + ck * 8] = *(uint4v*)tmp;
    }
}

// ---------------- rank-1 bias precompute ----------------
__global__ __launch_bounds__(256) void bias_kernel(const unsigned short* __restrict__ whb,
                                                   const unsigned short* __restrict__ rhkb,
                                                   const float* __restrict__ r_w_bias,
                                                   const float* __restrict__ r_r_bias,
                                                   float* __restrict__ bias_k,
                                                   float* __restrict__ bias_r) {
    int id = blockIdx.x * 256 + threadIdx.x;
    if (id < 64 * 2048) {
        int bn = id >> 11, j = id & 2047;
        int b = bn >> 4, n = bn & 15;
        const unsigned short* kp = &whb[((size_t)j * 4 + b) * 3072 + 1024 + n * 64];
        const float* wb = &r_w_bias[n * 64];
        float acc = 0.f;
#pragma unroll
        for (int d = 0; d < 64; ++d) acc += wb[d] * bf2f(kp[d]);
        bias_k[id] = acc;
    } else {
        int id2 = id - 64 * 2048;
        if (id2 < 16 * 2048) {
            int n = id2 >> 11, rel = id2 & 2047;
            const unsigned short* rp = &rhkb[(size_t)rel * 1024 + n * 64];
            const float* rb = &r_r_bias[n * 64];
            float acc = 0.f;
#pragma unroll
            for (int d = 0; d < 64; ++d) acc += rb[d] * bf2f(rp[d]);
            bias_r[id2] = acc;
        }
    }
}

// ---------------- MFMA flash attention (3 blocks/CU, balanced 1D grid) ----------------
// Per-wave scratch WS[wq] is time-shared: BD band (bf16, [80 band][20 q-pitch]) during
// score assembly, then P staging ([16 q][64 k] swizzled) for PV. Same-wave in-order DS
// ops + full data capture into sv[] before P writes make the union safe.
__global__ __launch_bounds__(256) void flash_attn_mfma(const unsigned short* __restrict__ whb,
                                                       const unsigned short* __restrict__ rhkb,
                                                       const unsigned short* __restrict__ vtg,
                                                       const float* __restrict__ bias_k,
                                                       const float* __restrict__ bias_r,
                                                       unsigned short* __restrict__ avb) {
    const int bid = blockIdx.x;
    const int bn = bid >> 4;
    const int bx = 15 - (bid & 15);   // long blocks first, balanced mix per CU
    const int b = bn >> 4, n = bn & 15, nb = n * 64;
    const int i0 = bx << 6;
    const int tid = threadIdx.x;
    const int wq = tid >> 6;
    const int lane = tid & 63;
    const int rg = lane >> 4;
    const int lc = lane & 15;

    __shared__ __align__(16) unsigned short Ks[4096];    // [key][64d] swizzled (8 KB)
    __shared__ __align__(16) unsigned short Rs[8192];    // 2 circular slots [64][64d] (16 KB)
    __shared__ __align__(16) unsigned short Vt[4096];    // [d][64key] swizzled (8 KB)
    __shared__ __align__(16) unsigned short WS[4][1600]; // per-wave union: BD band / P (12.5 KB)

    // persistent Q fragments
    bf16x8 qf[2];
    {
        const int qrow = MLEN + i0 + wq * 16 + lc;
        const unsigned short* qp = whb + ((size_t)qrow * 4 + b) * 3072 + nb + rg * 8;
        qf[0] = *(const bf16x8*)(qp);
        qf[1] = *(const bf16x8*)(qp + 32);
    }

    f32x4 Oacc[4] = {};
    float mrun[4] = {-INFINITY, -INFINITY, -INFINITY, -INFINITY};
    float lrun[4] = {0.f, 0.f, 0.f, 0.f};

    const int ntiles = bx + 17;

    // ---- prologue: prefetch tile 0 into registers ----
    uint4v pk[2], pv[2], pr[4];
    {
#pragma unroll
        for (int g = 0; g < 2; ++g) {
            const int f = g * 256 + tid;
            const int row = f >> 3, c = f & 7;
            pk[g] = *(const uint4v*)&whb[((size_t)row * 4 + b) * 3072 + 1024 + nb + c * 8];
            pv[g] = *(const uint4v*)&vtg[(size_t)bn * 131072 + (size_t)row * 2048 + c * 8];
        }
        const int relbase0 = 960 - i0;  // >= 0 for bx <= 15
#pragma unroll
        for (int g2 = 0; g2 < 4; ++g2) {
            const int row = g2 * 32 + (tid >> 3);
            const int c = tid & 7;
            int a = relbase0 + row;
            if (a > 2047) a = 2047;
            pr[g2] = *(const uint4v*)&rhkb[(size_t)a * 1024 + nb + c * 8];
        }
    }

    for (int kt = 0; kt < ntiles; ++kt) {
        const int jt0 = kt << 6;
        const int relbase = jt0 - i0 + 960;
        __syncthreads();  // previous compute done reading LDS

        // ---- write prefetched regs -> LDS ----
#pragma unroll
        for (int g = 0; g < 2; ++g) {
            const int f = g * 256 + tid;
            const int row = f >> 3, c = f & 7;
            *(uint4v*)&Ks[row * 64 + ((c ^ (row & 7)) << 3)] = pk[g];
            *(uint4v*)&Vt[row * 64 + ((c ^ (row & 7)) << 3)] = pv[g];
        }
        if (kt == 0) {
#pragma unroll
            for (int g2 = 0; g2 < 4; ++g2) {
                const int row = g2 * 32 + (tid >> 3);
                const int c = tid & 7;
                const int a = relbase + row;
                const int dst = ((a >> 6) & 1) * 4096 + (a & 63) * 64 + ((c ^ (a & 7)) << 3);
                *(uint4v*)&Rs[dst] = pr[g2];
            }
        } else {
#pragma unroll
            for (int g2 = 0; g2 < 2; ++g2) {
                const int row = 64 + g2 * 32 + (tid >> 3);
                const int c = tid & 7;
                const int a = relbase + row;
                const int dst = ((a >> 6) & 1) * 4096 + (a & 63) * 64 + ((c ^ (a & 7)) << 3);
                *(uint4v*)&Rs[dst] = pr[g2];
            }
        }
        // ---- issue next-tile prefetch into regs ----
        if (kt + 1 < ntiles) {
            const int jn = jt0 + 64;
#pragma unroll
            for (int g = 0; g < 2; ++g) {
                const int f = g * 256 + tid;
                const int row = f >> 3, c = f & 7;
                pk[g] = *(const uint4v*)&whb[((size_t)(jn + row) * 4 + b) * 3072 + 1024 + nb + c * 8];
                pv[g] = *(const uint4v*)&vtg[(size_t)bn * 131072 + (size_t)row * 2048 + jn + c * 8];
            }
            const int rbn = relbase + 64;
#pragma unroll
            for (int g2 = 0; g2 < 2; ++g2) {
                const int row = 64 + g2 * 32 + (tid >> 3);
                const int c = tid & 7;
                int a = rbn + row;
                if (a > 2047) a = 2047;
                pr[g2] = *(const uint4v*)&rhkb[(size_t)a * 1024 + nb + c * 8];
            }
        }
        __syncthreads();  // LDS tiles ready

        // ---- AC = Q.K^T ----
        f32x4 Sacc[4];
#pragma unroll
        for (int nf = 0; nf < 4; ++nf) {
            const int key = nf * 16 + lc;
            const int c7 = key & 7;
            const bf16x8 kf0 = *(const bf16x8*)&Ks[key * 64 + ((rg ^ c7) << 3)];
            const bf16x8 kf1 = *(const bf16x8*)&Ks[key * 64 + (((4 + rg) ^ c7) << 3)];
            f32x4 z = {0.f, 0.f, 0.f, 0.f};
            z = __builtin_amdgcn_mfma_f32_16x16x32_bf16(qf[0], kf0, z, 0, 0, 0);
            Sacc[nf] = __builtin_amdgcn_mfma_f32_16x16x32_bf16(qf[1], kf1, z, 0, 0, 0);
        }

        // ---- BD band = Q.Rwin^T + bias_r, bf16 transposed store into WS ----
        unsigned short* bdt = &WS[wq][0];
        const int nflo = 3 - wq;
#pragma unroll
        for (int e5 = 0; e5 < 5; ++e5) {
            const int nf8 = nflo + e5;
            const int a = relbase + nf8 * 16 + lc;
            const int rbase = ((a >> 6) & 1) * 4096 + (a & 63) * 64;
            const int c7 = a & 7;
            const bf16x8 rf0 = *(const bf16x8*)&Rs[rbase + ((rg ^ c7) << 3)];
            const bf16x8 rf1 = *(const bf16x8*)&Rs[rbase + (((4 + rg) ^ c7) << 3)];
            f32x4 bd = {0.f, 0.f, 0.f, 0.f};
            bd = __builtin_amdgcn_mfma_f32_16x16x32_bf16(qf[0], rf0, bd, 0, 0, 0);
            bd = __builtin_amdgcn_mfma_f32_16x16x32_bf16(qf[1], rf1, bd, 0, 0, 0);
            const int aa = a > 2047 ? 2047 : a;
            const float brv = bias_r[n * 2048 + aa];
            const int bb = e5 * 16 + lc;  // band offset in [0,80)
            ushort4 p4 = {f2bf(bd[0] + brv), f2bf(bd[1] + brv),
                          f2bf(bd[2] + brv), f2bf(bd[3] + brv)};
            *(ushort4*)&bdt[bb * 20 + rg * 4] = p4;
        }

        // ---- scores (captures all band reads into sv) ----
        float sv[4][4];
        float tmax[4] = {-INFINITY, -INFINITY, -INFINITY, -INFINITY};
#pragma unroll
        for (int nf = 0; nf < 4; ++nf) {
            const int jl = nf * 16 + lc;
            const float bkv = bias_k[(size_t)bn * 2048 + jt0 + jl];
#pragma unroll
            for (int r = 0; r < 4; ++r) {
                const int qr = rg * 4 + r;
                const int bb = 15 + jl - qr;           // band offset (wq-independent)
                float s = Sacc[nf][r] + bkv + bf2f(bdt[bb * 20 + qr]);
                const int o = 63 + jl - wq * 16 - qr;
                s = (relbase + o <= 2047) ? s * 0.125f : -INFINITY;
                sv[nf][r] = s;
                tmax[r] = fmaxf(tmax[r], s);
            }
        }
        float ef[4];
#pragma unroll
        for (int r = 0; r < 4; ++r) {
            float tm = tmax[r];
            tm = fmaxf(tm, __shfl_xor(tm, 1));
            tm = fmaxf(tm, __shfl_xor(tm, 2));
            tm = fmaxf(tm, __shfl_xor(tm, 4));
            tm = fmaxf(tm, __shfl_xor(tm, 8));
            const float mn = fmaxf(mrun[r], tm);
            ef[r] = __expf(mrun[r] - mn);
            mrun[r] = mn;
        }
        // ---- exp + stage P into the same per-wave scratch (band reads all done) ----
        float rsum[4] = {0.f, 0.f, 0.f, 0.f};
#pragma unroll
        for (int nf = 0; nf < 4; ++nf) {
            const int jl = nf * 16 + lc;
#pragma unroll
            for (int r = 0; r < 4; ++r) {
                const int qr = rg * 4 + r;
                const float p = __expf(sv[nf][r] - mrun[r]);
                rsum[r] += p;
                bdt[qr * 64 + (((jl >> 3) ^ (qr & 7)) << 3) + (jl & 7)] = f2bf(p);
            }
        }
#pragma unroll
        for (int r = 0; r < 4; ++r) {
            float rs = rsum[r];
            rs += __shfl_xor(rs, 1);
            rs += __shfl_xor(rs, 2);
            rs += __shfl_xor(rs, 4);
            rs += __shfl_xor(rs, 8);
            lrun[r] = lrun[r] * ef[r] + rs;
        }
#pragma unroll
        for (int nf = 0; nf < 4; ++nf)
#pragma unroll
            for (int r = 0; r < 4; ++r) Oacc[nf][r] *= ef[r];

        // ---- PV ----
        {
            const int c7 = lc & 7;
            const bf16x8 pf0 = *(const bf16x8*)&bdt[lc * 64 + ((rg ^ c7) << 3)];
            const bf16x8 pf1 = *(const bf16x8*)&bdt[lc * 64 + (((4 + rg) ^ c7) << 3)];
#pragma unroll
            for (int nf = 0; nf < 4; ++nf) {
                const int d = nf * 16 + lc;
                const int d7 = d & 7;
                const bf16x8 vf0 = *(const bf16x8*)&Vt[d * 64 + ((rg ^ d7) << 3)];
                const bf16x8 vf1 = *(const bf16x8*)&Vt[d * 64 + (((4 + rg) ^ d7) << 3)];
                Oacc[nf] = __builtin_amdgcn_mfma_f32_16x16x32_bf16(pf0, vf0, Oacc[nf], 0, 0, 0);
                Oacc[nf] = __builtin_amdgcn_mfma_f32_16x16x32_bf16(pf1, vf1, Oacc[nf], 0, 0, 0);
            }
        }
    }

    // ---- epilogue ----
    float inv[4];
#pragma unroll
    for (int r = 0; r < 4; ++r) inv[r] = 1.0f / lrun[r];
#pragma unroll
    for (int nf = 0; nf < 4; ++nf) {
        const int d = nf * 16 + lc;
#pragma unroll
        for (int r = 0; r < 4; ++r) {
            const int iq = i0 + wq * 16 + rg * 4 + r;
            avb[((size_t)iq * 4 + b) * 1024 + nb + d] = f2bf(Oacc[nf][r] * inv[r]);
        }
    }
}

// ---------------- residual add + layernorm ----------------
__global__ __launch_bounds__(256) void add_ln_kernel(const float* __restrict__ a,
                                                     const float* __restrict__ b,
                                                     const float* __restrict__ w,
                                                     const float* __restrict__ bias,
                                                     float* __restrict__ out,
                                                     unsigned short* __restrict__ out_bf) {
    const int row = blockIdx.x;
    const int t = threadIdx.x;
    __shared__ float xs[DM];
    __shared__ float red[256];

    const float* ar = a + (size_t)row * DM;
    const float* br = b + (size_t)row * DM;

    float lsum = 0.f;
#pragma unroll
    for (int c = t; c < DM; c += 256) {
        float v = ar[c] + br[c];
        xs[c] = v;
        lsum += v;
    }
    red[t] = lsum;
    __syncthreads();
    for (int off = 128; off > 0; off >>= 1) {
        if (t < off) red[t] += red[t + off];
        __syncthreads();
    }
    const float mu = red[0] * (1.0f / DM);
    __syncthreads();

    float lvar = 0.f;
#pragma unroll
    for (int c = t; c < DM; c += 256) {
        float dv = xs[c] - mu;
        lvar += dv * dv;
    }
    red[t] = lvar;
    __syncthreads();
    for (int off = 128; off > 0; off >>= 1) {
        if (t < off) red[t] += red[t + off];
        __syncthreads();
    }
    const float rstd = rsqrtf(red[0] * (1.0f / DM) + LN_EPS);
    __syncthreads();

    float* orow = out + (size_t)row * DM;
#pragma unroll
    for (int c = t; c < DM; c += 256) {
        float v = (xs[c] - mu) * rstd * w[c] + bias[c];
        orow[c] = v;
        if (out_bf) out_bf[(size_t)row * DM + c] = f2bf(v);
    }
}

extern "C" void kernel_launch(void* const* d_in, const int* in_sizes, int n_in,
                              void* d_out, int out_size, void* d_ws, size_t ws_size,
                              hipStream_t stream) {
    const float* dec_inp  = (const float*)d_in[0];
    const float* r        = (const float*)d_in[1];
    const float* r_w_bias = (const float*)d_in[2];
    const float* r_r_bias = (const float*)d_in[3];
    const float* mems     = (const float*)d_in[4];
    const float* qkv_w    = (const float*)d_in[6];
    const float* r_w      = (const float*)d_in[7];
    const float* o_w      = (const float*)d_in[8];
    const float* ln1_w    = (const float*)d_in[9];
    const float* ln1_b    = (const float*)d_in[10];
    const float* ln2_w    = (const float*)d_in[11];
    const float* ln2_b    = (const float*)d_in[12];
    const float* ff_w1    = (const float*)d_in[13];
    const float* ff_b1    = (const float*)d_in[14];
    const float* ff_w2    = (const float*)d_in[15];
    const float* ff_b2    = (const float*)d_in[16];
    float* out = (float*)d_out;
    char* ws = (char*)d_ws;

    unsigned short* catb  = (unsigned short*)(ws + OFF_CATB);
    unsigned short* vtg   = (unsigned short*)(ws + OFF_VTG);
    unsigned short* whb   = (unsigned short*)(ws + OFF_WHB);
    unsigned short* rb    = (unsigned short*)(ws + OFF_RB);
    unsigned short* rhkb  = (unsigned short*)(ws + OFF_RHKB);
    unsigned short* avb   = (unsigned short*)(ws + OFF_AVB);
    float*          tmp   = (float*)(ws + OFF_TMP);
    float*          ln1f  = (float*)(ws + OFF_LN1F);
    unsigned short* ln1b  = (unsigned short*)(ws + OFF_LN1B);
    unsigned short* ffhb  = (unsigned short*)(ws + OFF_FFHB);
    unsigned short* qkvwT = (unsigned short*)(ws + OFF_QKVWT);
    unsigned short* rwT   = (unsigned short*)(ws + OFF_RWT);
    unsigned short* owT   = (unsigned short*)(ws + OFF_OWT);
    unsigned short* ffw1T = (unsigned short*)(ws + OFF_FFW1T);
    unsigned short* ffw2T = (unsigned short*)(ws + OFF_FFW2T);
    float*          bk    = (float*)(ws + OFF_BK);
    float*          brr   = (float*)(ws + OFF_BR);

    // casts & weight transposes
    cast_cat<<<dim3(4096), 256, 0, stream>>>(mems, dec_inp, catb);
    cast_f32_bf16<<<dim3(1024), 256, 0, stream>>>(r, rb);
    transpose_cast<<<dim3(96, 32), 256, 0, stream>>>(qkv_w, qkvwT, 1024, 3072);
    transpose_cast<<<dim3(32, 32), 256, 0, stream>>>(r_w, rwT, 1024, 1024);
    transpose_cast<<<dim3(32, 32), 256, 0, stream>>>(o_w, owT, 1024, 1024);
    transpose_cast<<<dim3(128, 32), 256, 0, stream>>>(ff_w1, ffw1T, 1024, 4096);
    transpose_cast<<<dim3(32, 128), 256, 0, stream>>>(ff_w2, ffw2T, 4096, 1024);

    // projections
    gemm_bf16<<<dim3(24, 64), 256, 0, stream>>>(catb, qkvwT, nullptr, whb,
                                                KLEN * BSZ, 3 * NHD, DM, 4);
    gemm_bf16<<<dim3(8, 16), 256, 0, stream>>>(rb, rwT, nullptr, rhkb,
                                               KLEN, NHD, DM, 4);

    // attention precomputes (catb dead now; vtg reuses it)
    vtrans<<<dim3(32, 64), 256, 0, stream>>>(whb, vtg);
    bias_kernel<<<dim3(640), 256, 0, stream>>>(whb, rhkb, r_w_bias, r_r_bias, bk, brr);

    // MFMA flash attention (1D balanced grid)
    flash_attn_mfma<<<dim3(1024), 256, 0, stream>>>(
        whb, rhkb, vtg, bk, brr, avb);

    // output projection + LN + FFN + LN
    gemm_bf16<<<dim3(8, 32), 256, 0, stream>>>(avb, owT, nullptr, tmp,
                                               QLEN * BSZ, DM, NHD, 0);
    add_ln_kernel<<<dim3(QLEN * BSZ), 256, 0, stream>>>(
        dec_inp, tmp, ln1_w, ln1_b, ln1f, ln1b);
    gemm_bf16<<<dim3(32, 32), 256, 0, stream>>>(ln1b, ffw1T, ff_b1, ffhb,
                                                QLEN * BSZ, DI, DM, 1 | 2 | 4);
    gemm_bf16<<<dim3(8, 32), 256, 0, stream>>>(ffhb, ffw2T, ff_b2, tmp,
                                               QLEN * BSZ, DM, DI, 1);
    add_ln_kernel<<<dim3(QLEN * BSZ), 256, 0, stream>>>(
        ln1f, tmp, ln2_w, ln2_b, out, nullptr);
}

// Round 7
// 446.994 us; speedup vs baseline: 1.2435x; 1.0525x over previous
//
#include <hip/hip_runtime.h>
#include <hip/hip_bf16.h>
#include <math.h>

#define QLEN 1024
#define MLEN 1024
#define BSZ 4
#define KLEN 2048
#define NH 16
#define DH 64
#define DM 1024
#define DI 4096
#define NHD 1024
#define LN_EPS 1e-5f

typedef short bf16x8 __attribute__((ext_vector_type(8)));
typedef float f32x4 __attribute__((ext_vector_type(4)));
typedef unsigned int uint4v __attribute__((ext_vector_type(4)));

__device__ __forceinline__ float bf2f(unsigned short u) {
    union { unsigned u32; float f; } x; x.u32 = ((unsigned)u) << 16; return x.f;
}
__device__ __forceinline__ unsigned short f2bf(float f) {
    __hip_bfloat16 h = __float2bfloat16(f);
    return *(unsigned short*)&h;
}

// ---------------- workspace layout (BYTE offsets) ----------------
static const size_t OFF_CATB  = 0;           //  cat bf16 (dead after qkv gemm)
static const size_t OFF_VTG   = 0;           //  Vt_g bf16 [64 bn][64 d][2048 keys] (reuses CATB)
static const size_t OFF_WHB   = 16777216;    //  w_heads bf16 [8192][3072]
static const size_t OFF_RB    = 67108864;    //  r bf16 [2048][1024]
static const size_t OFF_RHKB  = 71303168;    //  r_head_k bf16 [2048][1024]
static const size_t OFF_AVB   = 75497472;    //  attn_vec bf16 [4096][1024]
static const size_t OFF_TMP   = 83886080;    //  tmp fp32 [4096][1024]
static const size_t OFF_LN1F  = 100663296;   //  ln1 fp32
static const size_t OFF_LN1B  = 117440512;   //  ln1 bf16
static const size_t OFF_FFHB  = 125829120;   //  ff_hid bf16 [4096][4096]
static const size_t OFF_QKVWT = 159383552;   //  qkv_w^T bf16 [3072][1024]
static const size_t OFF_RWT   = 165675008;   //  r_w^T bf16
static const size_t OFF_OWT   = 167772160;   //  o_w^T bf16
static const size_t OFF_FFW1T = 169869312;   //  ff_w1^T bf16
static const size_t OFF_FFW2T = 178257920;   //  ff_w2^T bf16
static const size_t OFF_BK    = 186646528;   //  bias_k fp32 [64 bn][2048] (pre-scaled by 1/8)
static const size_t OFF_BR    = 187170816;   //  bias_r fp32 [16 n][2048] (pre-scaled by 1/8)

// ---------------- casts ----------------
__global__ __launch_bounds__(256) void cast_cat(const float* __restrict__ mems,
                                                const float* __restrict__ dec,
                                                unsigned short* __restrict__ out) {
    size_t i8 = ((size_t)blockIdx.x * 256 + threadIdx.x) * 8;
    const size_t half = (size_t)MLEN * BSZ * DM;
    const float* src = (i8 < half) ? (mems + i8) : (dec + (i8 - half));
    float4 v0 = *(const float4*)src;
    float4 v1 = *(const float4*)(src + 4);
    ushort4 o0 = {f2bf(v0.x), f2bf(v0.y), f2bf(v0.z), f2bf(v0.w)};
    ushort4 o1 = {f2bf(v1.x), f2bf(v1.y), f2bf(v1.z), f2bf(v1.w)};
    *(ushort4*)&out[i8] = o0;
    *(ushort4*)&out[i8 + 4] = o1;
}

__global__ __launch_bounds__(256) void cast_f32_bf16(const float* __restrict__ in,
                                                     unsigned short* __restrict__ out) {
    size_t i8 = ((size_t)blockIdx.x * 256 + threadIdx.x) * 8;
    float4 v0 = *(const float4*)(in + i8);
    float4 v1 = *(const float4*)(in + i8 + 4);
    ushort4 o0 = {f2bf(v0.x), f2bf(v0.y), f2bf(v0.z), f2bf(v0.w)};
    ushort4 o1 = {f2bf(v1.x), f2bf(v1.y), f2bf(v1.z), f2bf(v1.w)};
    *(ushort4*)&out[i8] = o0;
    *(ushort4*)&out[i8 + 4] = o1;
}

// in [K][N] fp32 -> out [N][K] bf16
__global__ __launch_bounds__(256) void transpose_cast(const float* __restrict__ in,
                                                      unsigned short* __restrict__ out,
                                                      int K, int N) {
    __shared__ float tile[32][33];
    const int t = threadIdx.x;
    const int n0 = blockIdx.x * 32;
    const int k0 = blockIdx.y * 32;
    const int r = t >> 3;
    const int c0 = (t & 7) << 2;
    float4 v = *(const float4*)&in[(size_t)(k0 + r) * N + n0 + c0];
    tile[r][c0 + 0] = v.x; tile[r][c0 + 1] = v.y;
    tile[r][c0 + 2] = v.z; tile[r][c0 + 3] = v.w;
    __syncthreads();
    ushort4 o = {f2bf(tile[c0 + 0][r]), f2bf(tile[c0 + 1][r]),
                 f2bf(tile[c0 + 2][r]), f2bf(tile[c0 + 3][r])};
    *(ushort4*)&out[(size_t)(n0 + r) * K + k0 + c0] = o;
}

// ---------------- bf16 MFMA GEMM (proven: reg-staged dbuf + XOR swizzle) ------
__global__ __launch_bounds__(256) void gemm_bf16(const unsigned short* __restrict__ A,
                                                 const unsigned short* __restrict__ Bt,
                                                 const float* __restrict__ bias,
                                                 void* __restrict__ C,
                                                 int M, int N, int K, int flags) {
    __shared__ __align__(16) unsigned short As[128 * 64];
    __shared__ __align__(16) unsigned short Bs[128 * 64];

    const int tid = threadIdx.x;
    const int w = tid >> 6, l = tid & 63;
    const int wr = w >> 1, wc = w & 1;
    const int row0 = blockIdx.y * 128;
    const int col0 = blockIdx.x * 128;

    f32x4 acc[4][4] = {};

    uint4v ra[4], rb[4];
    {
#pragma unroll
        for (int q = 0; q < 4; ++q) {
            int f = q * 256 + tid, r = f >> 3, c = f & 7;
            ra[q] = *(const uint4v*)&A[(size_t)(row0 + r) * K + c * 8];
            rb[q] = *(const uint4v*)&Bt[(size_t)(col0 + r) * K + c * 8];
        }
    }

    const int nt = K >> 6;
    for (int kt = 0; kt < nt; ++kt) {
        __syncthreads();
#pragma unroll
        for (int q = 0; q < 4; ++q) {
            int f = q * 256 + tid, r = f >> 3, c = f & 7;
            int sw = (c ^ (r & 7)) << 3;
            *(uint4v*)&As[r * 64 + sw] = ra[q];
            *(uint4v*)&Bs[r * 64 + sw] = rb[q];
        }
        __syncthreads();
        if (kt + 1 < nt) {
            const int k0 = (kt + 1) << 6;
#pragma unroll
            for (int q = 0; q < 4; ++q) {
                int f = q * 256 + tid, r = f >> 3, c = f & 7;
                ra[q] = *(const uint4v*)&A[(size_t)(row0 + r) * K + k0 + c * 8];
                rb[q] = *(const uint4v*)&Bt[(size_t)(col0 + r) * K + k0 + c * 8];
            }
        }
#pragma unroll
        for (int ks = 0; ks < 2; ++ks) {
            bf16x8 a[4], bfr[4];
#pragma unroll
            for (int m = 0; m < 4; ++m) {
                int arow = wr * 64 + m * 16 + (l & 15);
                int chunk = (ks * 4 + (l >> 4)) ^ (arow & 7);
                a[m] = *(const bf16x8*)&As[arow * 64 + chunk * 8];
            }
#pragma unroll
            for (int n = 0; n < 4; ++n) {
                int brow = wc * 64 + n * 16 + (l & 15);
                int chunk = (ks * 4 + (l >> 4)) ^ (brow & 7);
                bfr[n] = *(const bf16x8*)&Bs[brow * 64 + chunk * 8];
            }
#pragma unroll
            for (int m = 0; m < 4; ++m)
#pragma unroll
                for (int n = 0; n < 4; ++n)
                    acc[m][n] = __builtin_amdgcn_mfma_f32_16x16x32_bf16(a[m], bfr[n], acc[m][n], 0, 0, 0);
        }
    }

#pragma unroll
    for (int n = 0; n < 4; ++n) {
        const int ccol = col0 + wc * 64 + n * 16 + (l & 15);
        const float bv = (flags & 1) ? bias[ccol] : 0.0f;
#pragma unroll
        for (int m = 0; m < 4; ++m) {
            const int crow0 = row0 + wr * 64 + m * 16 + ((l >> 4) << 2);
#pragma unroll
            for (int reg = 0; reg < 4; ++reg) {
                float v = acc[m][n][reg] + bv;
                if (flags & 2) v = fmaxf(v, 0.0f);
                if (flags & 4)
                    ((unsigned short*)C)[(size_t)(crow0 + reg) * N + ccol] = f2bf(v);
                else
                    ((float*)C)[(size_t)(crow0 + reg) * N + ccol] = v;
            }
        }
    }
}

// ---------------- V transpose to global: Vt_g[bn][d][key] ----------------
__global__ __launch_bounds__(256) void vtrans(const unsigned short* __restrict__ whb,
                                              unsigned short* __restrict__ vtg) {
    __shared__ unsigned short tile[64][72];
    const int bn = blockIdx.y;
    const int b = bn >> 4, n = bn & 15, nb = n * 64;
    const int jt0 = blockIdx.x * 64;
    const int tid = threadIdx.x;
#pragma unroll
    for (int g = 0; g < 2; ++g) {
        int f = g * 256 + tid;
        int key = f >> 3, c = f & 7;
        uint4v v = *(const uint4v*)&whb[((size_t)(jt0 + key) * 4 + b) * 3072 + 2048 + nb + c * 8];
        *(uint4v*)&tile[key][c * 8] = v;
    }
    __syncthreads();
#pragma unroll
    for (int g = 0; g < 2; ++g) {
        int f = g * 256 + tid;
        int d = f >> 3, ck = f & 7;
        unsigned short tmp[8];
#pragma unroll
        for (int e = 0; e < 8; ++e) tmp[e] = tile[ck * 8 + e][d];
        *(uint4v*)&vtg[(size_t)bn * 131072 + (size_t)d * 2048 + jt0 + ck * 8] = *(uint4v*)tmp;
    }
}

// ---------------- rank-1 bias precompute (pre-scaled by 1/8) ----------------
__global__ __launch_bounds__(256) void bias_kernel(const unsigned short* __restrict__ whb,
                                                   const unsigned short* __restrict__ rhkb,
                                                   const float* __restrict__ r_w_bias,
                                                   const float* __restrict__ r_r_bias,
                                                   float* __restrict__ bias_k,
                                                   float* __restrict__ bias_r) {
    int id = blockIdx.x * 256 + threadIdx.x;
    if (id < 64 * 2048) {
        int bn = id >> 11, j = id & 2047;
        int b = bn >> 4, n = bn & 15;
        const unsigned short* kp = &whb[((size_t)j * 4 + b) * 3072 + 1024 + n * 64];
        const float* wb = &r_w_bias[n * 64];
        float acc = 0.f;
#pragma unroll
        for (int d = 0; d < 64; ++d) acc += wb[d] * bf2f(kp[d]);
        bias_k[id] = acc * 0.125f;
    } else {
        int id2 = id - 64 * 2048;
        if (id2 < 16 * 2048) {
            int n = id2 >> 11, rel = id2 & 2047;
            const unsigned short* rp = &rhkb[(size_t)rel * 1024 + n * 64];
            const float* rb = &r_r_bias[n * 64];
            float acc = 0.f;
#pragma unroll
            for (int d = 0; d < 64; ++d) acc += rb[d] * bf2f(rp[d]);
            bias_r[id2] = acc * 0.125f;
        }
    }
}

// ---------------- MFMA flash attention: QBLK=128, 8 waves, full grid co-resident ------
// Wave wq (0..7) owns q rows [i0+wq*16, +16). R window: 192 rows, 4x64 circular slots.
// Q pre-scaled by 1/8 (exact bf16 exponent decrement); bias_k/bias_r pre-scaled.
__global__ __launch_bounds__(512) void flash_attn_mfma(const unsigned short* __restrict__ whb,
                                                       const unsigned short* __restrict__ rhkb,
                                                       const unsigned short* __restrict__ vtg,
                                                       const float* __restrict__ bias_k,
                                                       const float* __restrict__ bias_r,
                                                       unsigned short* __restrict__ avb) {
    const int bid = blockIdx.x;
    const int bn = bid >> 3;
    const int z = bid & 7;
    const int bx = (z & 1) ? (z >> 1) : 7 - (z >> 1);   // pair long+short per CU
    const int b = bn >> 4, n = bn & 15, nb = n * 64;
    const int i0 = bx << 7;
    const int tid = threadIdx.x;
    const int wq = tid >> 6;
    const int lane = tid & 63;
    const int rg = lane >> 4;
    const int lc = lane & 15;

    __shared__ __align__(16) unsigned short Ks[4096];     // [key][64d] swizzled (8 KB)
    __shared__ __align__(16) unsigned short Rs[16384];    // 4 circular slots [64][64d] (32 KB)
    __shared__ __align__(16) unsigned short Vt[4096];     // [d][64key] swizzled (8 KB)
    __shared__ __align__(16) unsigned short WS[8][1600];  // per-wave union: BD band / P (25 KB)

    // persistent Q fragments, pre-scaled by 1/8 (bf16 exponent -3, exact)
    bf16x8 qf[2];
    {
        const int qrow = MLEN + i0 + wq * 16 + lc;
        const unsigned short* qp = whb + ((size_t)qrow * 4 + b) * 3072 + nb + rg * 8;
        bf16x8 q0 = *(const bf16x8*)(qp);
        bf16x8 q1 = *(const bf16x8*)(qp + 32);
#pragma unroll
        for (int e = 0; e < 8; ++e) {
            unsigned short u0 = (unsigned short)q0[e];
            unsigned short u1 = (unsigned short)q1[e];
            qf[0][e] = (short)(((u0 & 0x7F80) > 0x0180) ? (unsigned short)(u0 - 0x0180)
                                                        : (unsigned short)(u0 & 0x8000));
            qf[1][e] = (short)(((u1 & 0x7F80) > 0x0180) ? (unsigned short)(u1 - 0x0180)
                                                        : (unsigned short)(u1 & 0x8000));
        }
    }

    f32x4 Oacc[4] = {};
    float mrun[4] = {-INFINITY, -INFINITY, -INFINITY, -INFINITY};
    float lrun[4] = {0.f, 0.f, 0.f, 0.f};

    const int ntiles = 2 * bx + 18;
    const int wbase_off = 112 - 16 * wq;   // band window start offset (per wave)

    const int srow = tid >> 3;   // 0..63 staging row
    const int sc = tid & 7;      // 0..7 staging 16B chunk

    // ---- prologue: prefetch tile 0 ----
    uint4v pk, pv, pr3[3];
    {
        pk = *(const uint4v*)&whb[((size_t)srow * 4 + b) * 3072 + 1024 + nb + sc * 8];
        pv = *(const uint4v*)&vtg[(size_t)bn * 131072 + (size_t)srow * 2048 + sc * 8];
        const int relbase0 = 896 - i0;   // >= 0 (i0 <= 896)
#pragma unroll
        for (int p = 0; p < 3; ++p) {
            const int a = relbase0 + p * 64 + srow;   // <= 1087, in range
            pr3[p] = *(const uint4v*)&rhkb[(size_t)a * 1024 + nb + sc * 8];
        }
    }

    for (int kt = 0; kt < ntiles; ++kt) {
        const int jt0 = kt << 6;
        const int relbase = jt0 - i0 + 896;
        __syncthreads();  // previous tile's compute done reading LDS

        // ---- write prefetched regs -> LDS ----
        *(uint4v*)&Ks[srow * 64 + ((sc ^ (srow & 7)) << 3)] = pk;
        *(uint4v*)&Vt[srow * 64 + ((sc ^ (srow & 7)) << 3)] = pv;
        if (kt == 0) {
#pragma unroll
            for (int p = 0; p < 3; ++p) {
                const int a = relbase + p * 64 + srow;
                const int dst = ((a >> 6) & 3) * 4096 + (a & 63) * 64 + ((sc ^ (a & 7)) << 3);
                *(uint4v*)&Rs[dst] = pr3[p];
            }
        } else {
            const int a = relbase + 128 + srow;
            const int dst = ((a >> 6) & 3) * 4096 + (a & 63) * 64 + ((sc ^ (a & 7)) << 3);
            *(uint4v*)&Rs[dst] = pr3[0];
        }
        // ---- issue next-tile prefetch into regs ----
        if (kt + 1 < ntiles) {
            const int jn = jt0 + 64;
            pk = *(const uint4v*)&whb[((size_t)(jn + srow) * 4 + b) * 3072 + 1024 + nb + sc * 8];
            pv = *(const uint4v*)&vtg[(size_t)bn * 131072 + (size_t)srow * 2048 + jn + sc * 8];
            int a = relbase + 192 + srow;
            if (a > 2047) a = 2047;
            pr3[0] = *(const uint4v*)&rhkb[(size_t)a * 1024 + nb + sc * 8];
        }
        __syncthreads();  // LDS tiles ready

        // ---- AC = Q.K^T (pre-scaled) ----
        f32x4 Sacc[4];
        __builtin_amdgcn_s_setprio(1);
#pragma unroll
        for (int nf = 0; nf < 4; ++nf) {
            const int key = nf * 16 + lc;
            const int c7 = key & 7;
            const bf16x8 kf0 = *(const bf16x8*)&Ks[key * 64 + ((rg ^ c7) << 3)];
            const bf16x8 kf1 = *(const bf16x8*)&Ks[key * 64 + (((4 + rg) ^ c7) << 3)];
            f32x4 zz = {0.f, 0.f, 0.f, 0.f};
            zz = __builtin_amdgcn_mfma_f32_16x16x32_bf16(qf[0], kf0, zz, 0, 0, 0);
            Sacc[nf] = __builtin_amdgcn_mfma_f32_16x16x32_bf16(qf[1], kf1, zz, 0, 0, 0);
        }
        __builtin_amdgcn_s_setprio(0);

        // ---- BD band = Q.Rwin^T + bias_r (all pre-scaled), bf16 transposed store ----
        unsigned short* bdt = &WS[wq][0];
        const int wbase = relbase + wbase_off;
#pragma unroll
        for (int e5 = 0; e5 < 5; ++e5) {
            const int a = wbase + e5 * 16 + lc;       // absolute rel row in window
            const int rbase = ((a >> 6) & 3) * 4096 + (a & 63) * 64;
            const int c7 = a & 7;
            const bf16x8 rf0 = *(const bf16x8*)&Rs[rbase + ((rg ^ c7) << 3)];
            const bf16x8 rf1 = *(const bf16x8*)&Rs[rbase + (((4 + rg) ^ c7) << 3)];
            f32x4 bd = {0.f, 0.f, 0.f, 0.f};
            bd = __builtin_amdgcn_mfma_f32_16x16x32_bf16(qf[0], rf0, bd, 0, 0, 0);
            bd = __builtin_amdgcn_mfma_f32_16x16x32_bf16(qf[1], rf1, bd, 0, 0, 0);
            const int aa = a > 2047 ? 2047 : a;
            const float brv = bias_r[n * 2048 + aa];
            const int bb = e5 * 16 + lc;
            ushort4 p4 = {f2bf(bd[0] + brv), f2bf(bd[1] + brv),
                          f2bf(bd[2] + brv), f2bf(bd[3] + brv)};
            *(ushort4*)&bdt[bb * 20 + rg * 4] = p4;
        }

        // ---- scores (captures all band reads into sv) ----
        float sv[4][4];
        float tmax[4] = {-INFINITY, -INFINITY, -INFINITY, -INFINITY};
#pragma unroll
        for (int nf = 0; nf < 4; ++nf) {
            const int jl = nf * 16 + lc;
            const float bkv = bias_k[(size_t)bn * 2048 + jt0 + jl];
            const int wbb = wbase + 15 + jl;   // = rel + qr; valid iff wbb - qr <= 2047
#pragma unroll
            for (int r = 0; r < 4; ++r) {
                const int qr = rg * 4 + r;
                const int bb = 15 + jl - qr;
                float s = Sacc[nf][r] + bkv + bf2f(bdt[bb * 20 + qr]);
                s = (wbb - qr <= 2047) ? s : -INFINITY;
                sv[nf][r] = s;
                tmax[r] = fmaxf(tmax[r], s);
            }
        }
        float ef[4];
#pragma unroll
        for (int r = 0; r < 4; ++r) {
            float tm = tmax[r];
            tm = fmaxf(tm, __shfl_xor(tm, 1));
            tm = fmaxf(tm, __shfl_xor(tm, 2));
            tm = fmaxf(tm, __shfl_xor(tm, 4));
            tm = fmaxf(tm, __shfl_xor(tm, 8));
            const float mn = fmaxf(mrun[r], tm);
            ef[r] = __expf(mrun[r] - mn);
            mrun[r] = mn;
        }
        // ---- exp + stage P into the same per-wave scratch (band reads all done) ----
        float rsum[4] = {0.f, 0.f, 0.f, 0.f};
#pragma unroll
        for (int nf = 0; nf < 4; ++nf) {
            const int jl = nf * 16 + lc;
#pragma unroll
            for (int r = 0; r < 4; ++r) {
                const int qr = rg * 4 + r;
                const float p = __expf(sv[nf][r] - mrun[r]);
                rsum[r] += p;
                bdt[qr * 64 + (((jl >> 3) ^ (qr & 7)) << 3) + (jl & 7)] = f2bf(p);
            }
        }
#pragma unroll
        for (int r = 0; r < 4; ++r) {
            float rs = rsum[r];
            rs += __shfl_xor(rs, 1);
            rs += __shfl_xor(rs, 2);
            rs += __shfl_xor(rs, 4);
            rs += __shfl_xor(rs, 8);
            lrun[r] = lrun[r] * ef[r] + rs;
        }
#pragma unroll
        for (int nf = 0; nf < 4; ++nf)
#pragma unroll
            for (int r = 0; r < 4; ++r) Oacc[nf][r] *= ef[r];

        // ---- PV ----
        {
            const int c7 = lc & 7;
            const bf16x8 pf0 = *(const bf16x8*)&bdt[lc * 64 + ((rg ^ c7) << 3)];
            const bf16x8 pf1 = *(const bf16x8*)&bdt[lc * 64 + (((4 + rg) ^ c7) << 3)];
            __builtin_amdgcn_s_setprio(1);
#pragma unroll
            for (int nf = 0; nf < 4; ++nf) {
                const int d = nf * 16 + lc;
                const int d7 = d & 7;
                const bf16x8 vf0 = *(const bf16x8*)&Vt[d * 64 + ((rg ^ d7) << 3)];
                const bf16x8 vf1 = *(const bf16x8*)&Vt[d * 64 + (((4 + rg) ^ d7) << 3)];
                Oacc[nf] = __builtin_amdgcn_mfma_f32_16x16x32_bf16(pf0, vf0, Oacc[nf], 0, 0, 0);
                Oacc[nf] = __builtin_amdgcn_mfma_f32_16x16x32_bf16(pf1, vf1, Oacc[nf], 0, 0, 0);
            }
            __builtin_amdgcn_s_setprio(0);
        }
    }

    // ---- epilogue ----
    float inv[4];
#pragma unroll
    for (int r = 0; r < 4; ++r) inv[r] = 1.0f / lrun[r];
#pragma unroll
    for (int nf = 0; nf < 4; ++nf) {
        const int d = nf * 16 + lc;
#pragma unroll
        for (int r = 0; r < 4; ++r) {
            const int iq = i0 + wq * 16 + rg * 4 + r;
            avb[((size_t)iq * 4 + b) * 1024 + nb + d] = f2bf(Oacc[nf][r] * inv[r]);
        }
    }
}

// ---------------- residual add + layernorm ----------------
__global__ __launch_bounds__(256) void add_ln_kernel(const float* __restrict__ a,
                                                     const float* __restrict__ b,
                                                     const float* __restrict__ w,
                                                     const float* __restrict__ bias,
                                                     float* __restrict__ out,
                                                     unsigned short* __restrict__ out_bf) {
    const int row = blockIdx.x;
    const int t = threadIdx.x;
    __shared__ float xs[DM];
    __shared__ float red[256];

    const float* ar = a + (size_t)row * DM;
    const float* br = b + (size_t)row * DM;

    float lsum = 0.f;
#pragma unroll
    for (int c = t; c < DM; c += 256) {
        float v = ar[c] + br[c];
        xs[c] = v;
        lsum += v;
    }
    red[t] = lsum;
    __syncthreads();
    for (int off = 128; off > 0; off >>= 1) {
        if (t < off) red[t] += red[t + off];
        __syncthreads();
    }
    const float mu = red[0] * (1.0f / DM);
    __syncthreads();

    float lvar = 0.f;
#pragma unroll
    for (int c = t; c < DM; c += 256) {
        float dv = xs[c] - mu;
        lvar += dv * dv;
    }
    red[t] = lvar;
    __syncthreads();
    for (int off = 128; off > 0; off >>= 1) {
        if (t < off) red[t] += red[t + off];
        __syncthreads();
    }
    const float rstd = rsqrtf(red[0] * (1.0f / DM) + LN_EPS);
    __syncthreads();

    float* orow = out + (size_t)row * DM;
#pragma unroll
    for (int c = t; c < DM; c += 256) {
        float v = (xs[c] - mu) * rstd * w[c] + bias[c];
        orow[c] = v;
        if (out_bf) out_bf[(size_t)row * DM + c] = f2bf(v);
    }
}

extern "C" void kernel_launch(void* const* d_in, const int* in_sizes, int n_in,
                              void* d_out, int out_size, void* d_ws, size_t ws_size,
                              hipStream_t stream) {
    const float* dec_inp  = (const float*)d_in[0];
    const float* r        = (const float*)d_in[1];
    const float* r_w_bias = (const float*)d_in[2];
    const float* r_r_bias = (const float*)d_in[3];
    const float* mems     = (const float*)d_in[4];
    const float* qkv_w    = (const float*)d_in[6];
    const float* r_w      = (const float*)d_in[7];
    const float* o_w      = (const float*)d_in[8];
    const float* ln1_w    = (const float*)d_in[9];
    const float* ln1_b    = (const float*)d_in[10];
    const float* ln2_w    = (const float*)d_in[11];
    const float* ln2_b    = (const float*)d_in[12];
    const float* ff_w1    = (const float*)d_in[13];
    const float* ff_b1    = (const float*)d_in[14];
    const float* ff_w2    = (const float*)d_in[15];
    const float* ff_b2    = (const float*)d_in[16];
    float* out = (float*)d_out;
    char* ws = (char*)d_ws;

    unsigned short* catb  = (unsigned short*)(ws + OFF_CATB);
    unsigned short* vtg   = (unsigned short*)(ws + OFF_VTG);
    unsigned short* whb   = (unsigned short*)(ws + OFF_WHB);
    unsigned short* rb    = (unsigned short*)(ws + OFF_RB);
    unsigned short* rhkb  = (unsigned short*)(ws + OFF_RHKB);
    unsigned short* avb   = (unsigned short*)(ws + OFF_AVB);
    float*          tmp   = (float*)(ws + OFF_TMP);
    float*          ln1f  = (float*)(ws + OFF_LN1F);
    unsigned short* ln1b  = (unsigned short*)(ws + OFF_LN1B);
    unsigned short* ffhb  = (unsigned short*)(ws + OFF_FFHB);
    unsigned short* qkvwT = (unsigned short*)(ws + OFF_QKVWT);
    unsigned short* rwT   = (unsigned short*)(ws + OFF_RWT);
    unsigned short* owT   = (unsigned short*)(ws + OFF_OWT);
    unsigned short* ffw1T = (unsigned short*)(ws + OFF_FFW1T);
    unsigned short* ffw2T = (unsigned short*)(ws + OFF_FFW2T);
    float*          bk    = (float*)(ws + OFF_BK);
    float*          brr   = (float*)(ws + OFF_BR);

    // casts & weight transposes
    cast_cat<<<dim3(4096), 256, 0, stream>>>(mems, dec_inp, catb);
    cast_f32_bf16<<<dim3(1024), 256, 0, stream>>>(r, rb);
    transpose_cast<<<dim3(96, 32), 256, 0, stream>>>(qkv_w, qkvwT, 1024, 3072);
    transpose_cast<<<dim3(32, 32), 256, 0, stream>>>(r_w, rwT, 1024, 1024);
    transpose_cast<<<dim3(32, 32), 256, 0, stream>>>(o_w, owT, 1024, 1024);
    transpose_cast<<<dim3(128, 32), 256, 0, stream>>>(ff_w1, ffw1T, 1024, 4096);
    transpose_cast<<<dim3(32, 128), 256, 0, stream>>>(ff_w2, ffw2T, 4096, 1024);

    // projections
    gemm_bf16<<<dim3(24, 64), 256, 0, stream>>>(catb, qkvwT, nullptr, whb,
                                                KLEN * BSZ, 3 * NHD, DM, 4);
    gemm_bf16<<<dim3(8, 16), 256, 0, stream>>>(rb, rwT, nullptr, rhkb,
                                               KLEN, NHD, DM, 4);

    // attention precomputes (catb dead now; vtg reuses it)
    vtrans<<<dim3(32, 64), 256, 0, stream>>>(whb, vtg);
    bias_kernel<<<dim3(640), 256, 0, stream>>>(whb, rhkb, r_w_bias, r_r_bias, bk, brr);

    // MFMA flash attention: 512 blocks x 512 threads, fully co-resident
    flash_attn_mfma<<<dim3(512), 512, 0, stream>>>(
        whb, rhkb, vtg, bk, brr, avb);

    // output projection + LN + FFN + LN
    gemm_bf16<<<dim3(8, 32), 256, 0, stream>>>(avb, owT, nullptr, tmp,
                                               QLEN * BSZ, DM, NHD, 0);
    add_ln_kernel<<<dim3(QLEN * BSZ), 256, 0, stream>>>(
        dec_inp, tmp, ln1_w, ln1_b, ln1f, ln1b);
    gemm_bf16<<<dim3(32, 32), 256, 0, stream>>>(ln1b, ffw1T, ff_b1, ffhb,
                                                QLEN * BSZ, DI, DM, 1 | 2 | 4);
    gemm_bf16<<<dim3(8, 32), 256, 0, stream>>>(ffhb, ffw2T, ff_b2, tmp,
                                               QLEN * BSZ, DM, DI, 1);
    add_ln_kernel<<<dim3(QLEN * BSZ), 256, 0, stream>>>(
        ln1f, tmp, ln2_w, ln2_b, out, nullptr);
}

// Round 8
// 444.646 us; speedup vs baseline: 1.2500x; 1.0053x over previous
//
#include <hip/hip_runtime.h>
#include <hip/hip_bf16.h>
#include <math.h>

#define QLEN 1024
#define MLEN 1024
#define BSZ 4
#define KLEN 2048
#define NH 16
#define DH 64
#define DM 1024
#define DI 4096
#define NHD 1024
#define LN_EPS 1e-5f

typedef short bf16x8 __attribute__((ext_vector_type(8)));
typedef float f32x4 __attribute__((ext_vector_type(4)));
typedef unsigned int uint4v __attribute__((ext_vector_type(4)));

__device__ __forceinline__ float bf2f(unsigned short u) {
    union { unsigned u32; float f; } x; x.u32 = ((unsigned)u) << 16; return x.f;
}
__device__ __forceinline__ unsigned short f2bf(float f) {
    __hip_bfloat16 h = __float2bfloat16(f);
    return *(unsigned short*)&h;
}

// ---------------- workspace layout (BYTE offsets) ----------------
static const size_t OFF_CATB  = 0;           //  cat bf16 (dead after qkv gemm)
static const size_t OFF_VTG   = 0;           //  Vt_g bf16 [64 bn][64 d][2048 keys] (reuses CATB)
static const size_t OFF_WHB   = 16777216;    //  w_heads bf16 [8192][3072]
static const size_t OFF_RB    = 67108864;    //  r bf16 [2048][1024]
static const size_t OFF_RHKB  = 71303168;    //  r_head_k bf16 [2048][1024]
static const size_t OFF_AVB   = 75497472;    //  attn_vec bf16 [4096][1024]
static const size_t OFF_TMP   = 83886080;    //  tmp fp32 [4096][1024]
static const size_t OFF_LN1F  = 100663296;   //  ln1 fp32
static const size_t OFF_LN1B  = 117440512;   //  ln1 bf16
static const size_t OFF_FFHB  = 125829120;   //  ff_hid bf16 [4096][4096]
static const size_t OFF_QKVWT = 159383552;   //  qkv_w^T bf16 [3072][1024]
static const size_t OFF_RWT   = 165675008;   //  r_w^T bf16
static const size_t OFF_OWT   = 167772160;   //  o_w^T bf16
static const size_t OFF_FFW1T = 169869312;   //  ff_w1^T bf16
static const size_t OFF_FFW2T = 178257920;   //  ff_w2^T bf16
static const size_t OFF_BK    = 186646528;   //  bias_k fp32 [64 bn][2048] (pre-scaled by 1/8)
static const size_t OFF_BR    = 187170816;   //  bias_r fp32 [16 n][2048] (pre-scaled by 1/8)

// ---------------- casts ----------------
__global__ __launch_bounds__(256) void cast_cat(const float* __restrict__ mems,
                                                const float* __restrict__ dec,
                                                unsigned short* __restrict__ out) {
    size_t i8 = ((size_t)blockIdx.x * 256 + threadIdx.x) * 8;
    const size_t half = (size_t)MLEN * BSZ * DM;
    const float* src = (i8 < half) ? (mems + i8) : (dec + (i8 - half));
    float4 v0 = *(const float4*)src;
    float4 v1 = *(const float4*)(src + 4);
    ushort4 o0 = {f2bf(v0.x), f2bf(v0.y), f2bf(v0.z), f2bf(v0.w)};
    ushort4 o1 = {f2bf(v1.x), f2bf(v1.y), f2bf(v1.z), f2bf(v1.w)};
    *(ushort4*)&out[i8] = o0;
    *(ushort4*)&out[i8 + 4] = o1;
}

__global__ __launch_bounds__(256) void cast_f32_bf16(const float* __restrict__ in,
                                                     unsigned short* __restrict__ out) {
    size_t i8 = ((size_t)blockIdx.x * 256 + threadIdx.x) * 8;
    float4 v0 = *(const float4*)(in + i8);
    float4 v1 = *(const float4*)(in + i8 + 4);
    ushort4 o0 = {f2bf(v0.x), f2bf(v0.y), f2bf(v0.z), f2bf(v0.w)};
    ushort4 o1 = {f2bf(v1.x), f2bf(v1.y), f2bf(v1.z), f2bf(v1.w)};
    *(ushort4*)&out[i8] = o0;
    *(ushort4*)&out[i8 + 4] = o1;
}

// all 5 weight transposes fused: [K][N] fp32 -> [N][K] bf16
__global__ __launch_bounds__(256) void transpose_cast_all(
        const float* __restrict__ qkv_w, const float* __restrict__ r_w,
        const float* __restrict__ o_w,  const float* __restrict__ ff_w1,
        const float* __restrict__ ff_w2,
        unsigned short* __restrict__ qkvwT, unsigned short* __restrict__ rwT,
        unsigned short* __restrict__ owT, unsigned short* __restrict__ ffw1T,
        unsigned short* __restrict__ ffw2T) {
    __shared__ float tile[32][33];
    const int bid = blockIdx.x;
    const float* in; unsigned short* out; int K, N, nx, lid;
    if (bid < 3072)      { in = qkv_w; out = qkvwT; K = 1024; N = 3072; nx = 96;  lid = bid; }
    else if (bid < 4096) { in = r_w;   out = rwT;   K = 1024; N = 1024; nx = 32;  lid = bid - 3072; }
    else if (bid < 5120) { in = o_w;   out = owT;   K = 1024; N = 1024; nx = 32;  lid = bid - 4096; }
    else if (bid < 9216) { in = ff_w1; out = ffw1T; K = 1024; N = 4096; nx = 128; lid = bid - 5120; }
    else                 { in = ff_w2; out = ffw2T; K = 4096; N = 1024; nx = 32;  lid = bid - 9216; }
    const int n0 = (lid % nx) * 32;
    const int k0 = (lid / nx) * 32;
    const int t = threadIdx.x;
    const int r = t >> 3;
    const int c0 = (t & 7) << 2;
    float4 v = *(const float4*)&in[(size_t)(k0 + r) * N + n0 + c0];
    tile[r][c0 + 0] = v.x; tile[r][c0 + 1] = v.y;
    tile[r][c0 + 2] = v.z; tile[r][c0 + 3] = v.w;
    __syncthreads();
    ushort4 o = {f2bf(tile[c0 + 0][r]), f2bf(tile[c0 + 1][r]),
                 f2bf(tile[c0 + 2][r]), f2bf(tile[c0 + 3][r])};
    *(ushort4*)&out[(size_t)(n0 + r) * K + k0 + c0] = o;
}

// ---------------- bf16 MFMA GEMM (proven: reg-staged dbuf + XOR swizzle) ------
__global__ __launch_bounds__(256) void gemm_bf16(const unsigned short* __restrict__ A,
                                                 const unsigned short* __restrict__ Bt,
                                                 const float* __restrict__ bias,
                                                 void* __restrict__ C,
                                                 int M, int N, int K, int flags) {
    __shared__ __align__(16) unsigned short As[128 * 64];
    __shared__ __align__(16) unsigned short Bs[128 * 64];

    const int tid = threadIdx.x;
    const int w = tid >> 6, l = tid & 63;
    const int wr = w >> 1, wc = w & 1;
    const int row0 = blockIdx.y * 128;
    const int col0 = blockIdx.x * 128;

    f32x4 acc[4][4] = {};

    uint4v ra[4], rb[4];
    {
#pragma unroll
        for (int q = 0; q < 4; ++q) {
            int f = q * 256 + tid, r = f >> 3, c = f & 7;
            ra[q] = *(const uint4v*)&A[(size_t)(row0 + r) * K + c * 8];
            rb[q] = *(const uint4v*)&Bt[(size_t)(col0 + r) * K + c * 8];
        }
    }

    const int nt = K >> 6;
    for (int kt = 0; kt < nt; ++kt) {
        __syncthreads();
#pragma unroll
        for (int q = 0; q < 4; ++q) {
            int f = q * 256 + tid, r = f >> 3, c = f & 7;
            int sw = (c ^ (r & 7)) << 3;
            *(uint4v*)&As[r * 64 + sw] = ra[q];
            *(uint4v*)&Bs[r * 64 + sw] = rb[q];
        }
        __syncthreads();
        if (kt + 1 < nt) {
            const int k0 = (kt + 1) << 6;
#pragma unroll
            for (int q = 0; q < 4; ++q) {
                int f = q * 256 + tid, r = f >> 3, c = f & 7;
                ra[q] = *(const uint4v*)&A[(size_t)(row0 + r) * K + k0 + c * 8];
                rb[q] = *(const uint4v*)&Bt[(size_t)(col0 + r) * K + k0 + c * 8];
            }
        }
#pragma unroll
        for (int ks = 0; ks < 2; ++ks) {
            bf16x8 a[4], bfr[4];
#pragma unroll
            for (int m = 0; m < 4; ++m) {
                int arow = wr * 64 + m * 16 + (l & 15);
                int chunk = (ks * 4 + (l >> 4)) ^ (arow & 7);
                a[m] = *(const bf16x8*)&As[arow * 64 + chunk * 8];
            }
#pragma unroll
            for (int n = 0; n < 4; ++n) {
                int brow = wc * 64 + n * 16 + (l & 15);
                int chunk = (ks * 4 + (l >> 4)) ^ (brow & 7);
                bfr[n] = *(const bf16x8*)&Bs[brow * 64 + chunk * 8];
            }
#pragma unroll
            for (int m = 0; m < 4; ++m)
#pragma unroll
                for (int n = 0; n < 4; ++n)
                    acc[m][n] = __builtin_amdgcn_mfma_f32_16x16x32_bf16(a[m], bfr[n], acc[m][n], 0, 0, 0);
        }
    }

#pragma unroll
    for (int n = 0; n < 4; ++n) {
        const int ccol = col0 + wc * 64 + n * 16 + (l & 15);
        const float bv = (flags & 1) ? bias[ccol] : 0.0f;
#pragma unroll
        for (int m = 0; m < 4; ++m) {
            const int crow0 = row0 + wr * 64 + m * 16 + ((l >> 4) << 2);
#pragma unroll
            for (int reg = 0; reg < 4; ++reg) {
                float v = acc[m][n][reg] + bv;
                if (flags & 2) v = fmaxf(v, 0.0f);
                if (flags & 4)
                    ((unsigned short*)C)[(size_t)(crow0 + reg) * N + ccol] = f2bf(v);
                else
                    ((float*)C)[(size_t)(crow0 + reg) * N + ccol] = v;
            }
        }
    }
}

// ---------------- V transpose to global: Vt_g[bn][d][key] ----------------
__global__ __launch_bounds__(256) void vtrans(const unsigned short* __restrict__ whb,
                                              unsigned short* __restrict__ vtg) {
    __shared__ unsigned short tile[64][72];
    const int bn = blockIdx.y;
    const int b = bn >> 4, n = bn & 15, nb = n * 64;
    const int jt0 = blockIdx.x * 64;
    const int tid = threadIdx.x;
#pragma unroll
    for (int g = 0; g < 2; ++g) {
        int f = g * 256 + tid;
        int key = f >> 3, c = f & 7;
        uint4v v = *(const uint4v*)&whb[((size_t)(jt0 + key) * 4 + b) * 3072 + 2048 + nb + c * 8];
        *(uint4v*)&tile[key][c * 8] = v;
    }
    __syncthreads();
#pragma unroll
    for (int g = 0; g < 2; ++g) {
        int f = g * 256 + tid;
        int d = f >> 3, ck = f & 7;
        unsigned short tmp[8];
#pragma unroll
        for (int e = 0; e < 8; ++e) tmp[e] = tile[ck * 8 + e][d];
        *(uint4v*)&vtg[(size_t)bn * 131072 + (size_t)d * 2048 + jt0 + ck * 8] = *(uint4v*)tmp;
    }
}

// ---------------- rank-1 bias precompute (pre-scaled by 1/8) ----------------
__global__ __launch_bounds__(256) void bias_kernel(const unsigned short* __restrict__ whb,
                                                   const unsigned short* __restrict__ rhkb,
                                                   const float* __restrict__ r_w_bias,
                                                   const float* __restrict__ r_r_bias,
                                                   float* __restrict__ bias_k,
                                                   float* __restrict__ bias_r) {
    int id = blockIdx.x * 256 + threadIdx.x;
    if (id < 64 * 2048) {
        int bn = id >> 11, j = id & 2047;
        int b = bn >> 4, n = bn & 15;
        const unsigned short* kp = &whb[((size_t)j * 4 + b) * 3072 + 1024 + n * 64];
        const float* wb = &r_w_bias[n * 64];
        float acc = 0.f;
#pragma unroll
        for (int d = 0; d < 64; ++d) acc += wb[d] * bf2f(kp[d]);
        bias_k[id] = acc * 0.125f;
    } else {
        int id2 = id - 64 * 2048;
        if (id2 < 16 * 2048) {
            int n = id2 >> 11, rel = id2 & 2047;
            const unsigned short* rp = &rhkb[(size_t)rel * 1024 + n * 64];
            const float* rb = &r_r_bias[n * 64];
            float acc = 0.f;
#pragma unroll
            for (int d = 0; d < 64; ++d) acc += rb[d] * bf2f(rp[d]);
            bias_r[id2] = acc * 0.125f;
        }
    }
}

// ---------------- MFMA flash attention: QBLK=128, 8 waves; band via shuffles ------
// BD band kept in registers; rel-shift realized as a 16-lane rotation:
//   score(qr, jl) needs bdp[e5][r] from lane (rg<<4)|((15+lc-qr)&15), e5 = nf + (lc>qr).
__global__ __launch_bounds__(512) void flash_attn_mfma(const unsigned short* __restrict__ whb,
                                                       const unsigned short* __restrict__ rhkb,
                                                       const unsigned short* __restrict__ vtg,
                                                       const float* __restrict__ bias_k,
                                                       const float* __restrict__ bias_r,
                                                       unsigned short* __restrict__ avb) {
    const int bid = blockIdx.x;
    const int bn = bid >> 3;
    const int z = bid & 7;
    const int bx = (z & 1) ? (z >> 1) : 7 - (z >> 1);   // pair long+short per CU
    const int b = bn >> 4, n = bn & 15, nb = n * 64;
    const int i0 = bx << 7;
    const int tid = threadIdx.x;
    const int wq = tid >> 6;
    const int lane = tid & 63;
    const int rg = lane >> 4;
    const int lc = lane & 15;

    __shared__ __align__(16) unsigned short Ks[4096];     // [key][64d] swizzled (8 KB)
    __shared__ __align__(16) unsigned short Rs[16384];    // 4 circular slots [64][64d] (32 KB)
    __shared__ __align__(16) unsigned short Vt[4096];     // [d][64key] swizzled (8 KB)
    __shared__ __align__(16) unsigned short Ps[8][1024];  // per-wave P [16 q][64 key] swizzled (16 KB)

    // persistent Q fragments, pre-scaled by 1/8 (bf16 exponent -3, exact)
    bf16x8 qf[2];
    {
        const int qrow = MLEN + i0 + wq * 16 + lc;
        const unsigned short* qp = whb + ((size_t)qrow * 4 + b) * 3072 + nb + rg * 8;
        bf16x8 q0 = *(const bf16x8*)(qp);
        bf16x8 q1 = *(const bf16x8*)(qp + 32);
#pragma unroll
        for (int e = 0; e < 8; ++e) {
            unsigned short u0 = (unsigned short)q0[e];
            unsigned short u1 = (unsigned short)q1[e];
            qf[0][e] = (short)(((u0 & 0x7F80) > 0x0180) ? (unsigned short)(u0 - 0x0180)
                                                        : (unsigned short)(u0 & 0x8000));
            qf[1][e] = (short)(((u1 & 0x7F80) > 0x0180) ? (unsigned short)(u1 - 0x0180)
                                                        : (unsigned short)(u1 & 0x8000));
        }
    }

    f32x4 Oacc[4] = {};
    float mrun[4] = {-INFINITY, -INFINITY, -INFINITY, -INFINITY};
    float lrun[4] = {0.f, 0.f, 0.f, 0.f};

    const int ntiles = 2 * bx + 18;
    const int wbase_off = 112 - 16 * wq;

    const int srow = tid >> 3;
    const int sc = tid & 7;

    // shuffle source lanes & e5-select predicates (per r, reused every tile)
    int srcl[4];
    bool hi5[4];
#pragma unroll
    for (int r = 0; r < 4; ++r) {
        const int qr = rg * 4 + r;
        srcl[r] = (rg << 4) | ((15 + lc - qr) & 15);
        hi5[r] = (lc > qr);
    }

    // ---- prologue: prefetch tile 0 ----
    uint4v pk, pv, pr3[3];
    {
        pk = *(const uint4v*)&whb[((size_t)srow * 4 + b) * 3072 + 1024 + nb + sc * 8];
        pv = *(const uint4v*)&vtg[(size_t)bn * 131072 + (size_t)srow * 2048 + sc * 8];
        const int relbase0 = 896 - i0;
#pragma unroll
        for (int p = 0; p < 3; ++p) {
            const int a = relbase0 + p * 64 + srow;
            pr3[p] = *(const uint4v*)&rhkb[(size_t)a * 1024 + nb + sc * 8];
        }
    }

    for (int kt = 0; kt < ntiles; ++kt) {
        const int jt0 = kt << 6;
        const int relbase = jt0 - i0 + 896;
        __syncthreads();

        // ---- write prefetched regs -> LDS ----
        *(uint4v*)&Ks[srow * 64 + ((sc ^ (srow & 7)) << 3)] = pk;
        *(uint4v*)&Vt[srow * 64 + ((sc ^ (srow & 7)) << 3)] = pv;
        if (kt == 0) {
#pragma unroll
            for (int p = 0; p < 3; ++p) {
                const int a = relbase + p * 64 + srow;
                const int dst = ((a >> 6) & 3) * 4096 + (a & 63) * 64 + ((sc ^ (a & 7)) << 3);
                *(uint4v*)&Rs[dst] = pr3[p];
            }
        } else {
            const int a = relbase + 128 + srow;
            const int dst = ((a >> 6) & 3) * 4096 + (a & 63) * 64 + ((sc ^ (a & 7)) << 3);
            *(uint4v*)&Rs[dst] = pr3[0];
        }
        // ---- issue next-tile prefetch into regs ----
        if (kt + 1 < ntiles) {
            const int jn = jt0 + 64;
            pk = *(const uint4v*)&whb[((size_t)(jn + srow) * 4 + b) * 3072 + 1024 + nb + sc * 8];
            pv = *(const uint4v*)&vtg[(size_t)bn * 131072 + (size_t)srow * 2048 + jn + sc * 8];
            int a = relbase + 192 + srow;
            if (a > 2047) a = 2047;
            pr3[0] = *(const uint4v*)&rhkb[(size_t)a * 1024 + nb + sc * 8];
        }
        __syncthreads();

        // ---- AC = Q.K^T (pre-scaled) ----
        f32x4 Sacc[4];
        __builtin_amdgcn_s_setprio(1);
#pragma unroll
        for (int nf = 0; nf < 4; ++nf) {
            const int key = nf * 16 + lc;
            const int c7 = key & 7;
            const bf16x8 kf0 = *(const bf16x8*)&Ks[key * 64 + ((rg ^ c7) << 3)];
            const bf16x8 kf1 = *(const bf16x8*)&Ks[key * 64 + (((4 + rg) ^ c7) << 3)];
            f32x4 zz = {0.f, 0.f, 0.f, 0.f};
            zz = __builtin_amdgcn_mfma_f32_16x16x32_bf16(qf[0], kf0, zz, 0, 0, 0);
            Sacc[nf] = __builtin_amdgcn_mfma_f32_16x16x32_bf16(qf[1], kf1, zz, 0, 0, 0);
        }
        __builtin_amdgcn_s_setprio(0);

        // ---- scores: rolling BD (2 live groups) + shuffle distribution ----
        const int wbase = relbase + wbase_off;
        const bool needmask = (wbase + 78 > 2047);
        float sv[4][4];
        float tmax[4] = {-INFINITY, -INFINITY, -INFINITY, -INFINITY};

        // bd group e5 = 0
        f32x4 bdpA;
        {
            const int a = wbase + lc;
            const int rbase = ((a >> 6) & 3) * 4096 + (a & 63) * 64;
            const int c7 = a & 7;
            const bf16x8 rf0 = *(const bf16x8*)&Rs[rbase + ((rg ^ c7) << 3)];
            const bf16x8 rf1 = *(const bf16x8*)&Rs[rbase + (((4 + rg) ^ c7) << 3)];
            f32x4 bd = {0.f, 0.f, 0.f, 0.f};
            bd = __builtin_amdgcn_mfma_f32_16x16x32_bf16(qf[0], rf0, bd, 0, 0, 0);
            bd = __builtin_amdgcn_mfma_f32_16x16x32_bf16(qf[1], rf1, bd, 0, 0, 0);
            const int aa = a > 2047 ? 2047 : a;
            const float brv = bias_r[n * 2048 + aa];
#pragma unroll
            for (int r = 0; r < 4; ++r) bdpA[r] = bd[r] + brv;
        }
#pragma unroll
        for (int nf = 0; nf < 4; ++nf) {
            // bd group e5 = nf+1
            f32x4 bdpB;
            {
                const int a = wbase + (nf + 1) * 16 + lc;
                const int rbase = ((a >> 6) & 3) * 4096 + (a & 63) * 64;
                const int c7 = a & 7;
                const bf16x8 rf0 = *(const bf16x8*)&Rs[rbase + ((rg ^ c7) << 3)];
                const bf16x8 rf1 = *(const bf16x8*)&Rs[rbase + (((4 + rg) ^ c7) << 3)];
                f32x4 bd = {0.f, 0.f, 0.f, 0.f};
                bd = __builtin_amdgcn_mfma_f32_16x16x32_bf16(qf[0], rf0, bd, 0, 0, 0);
                bd = __builtin_amdgcn_mfma_f32_16x16x32_bf16(qf[1], rf1, bd, 0, 0, 0);
                const int aa = a > 2047 ? 2047 : a;
                const float brv = bias_r[n * 2048 + aa];
#pragma unroll
                for (int r = 0; r < 4; ++r) bdpB[r] = bd[r] + brv;
            }
            const int jl = nf * 16 + lc;
            const float bkv = bias_k[(size_t)bn * 2048 + jt0 + jl];
#pragma unroll
            for (int r = 0; r < 4; ++r) {
                const float v0 = __shfl(bdpA[r], srcl[r]);
                const float v1 = __shfl(bdpB[r], srcl[r]);
                const float bdv = hi5[r] ? v1 : v0;
                float s = Sacc[nf][r] + bkv + bdv;
                if (needmask) {
                    const int qr = rg * 4 + r;
                    s = (wbase + 15 + jl - qr <= 2047) ? s : -INFINITY;
                }
                sv[nf][r] = s;
                tmax[r] = fmaxf(tmax[r], s);
            }
            bdpA = bdpB;
        }

        // ---- online softmax ----
        float ef[4];
#pragma unroll
        for (int r = 0; r < 4; ++r) {
            float tm = tmax[r];
            tm = fmaxf(tm, __shfl_xor(tm, 1));
            tm = fmaxf(tm, __shfl_xor(tm, 2));
            tm = fmaxf(tm, __shfl_xor(tm, 4));
            tm = fmaxf(tm, __shfl_xor(tm, 8));
            const float mn = fmaxf(mrun[r], tm);
            ef[r] = __expf(mrun[r] - mn);
            mrun[r] = mn;
        }
        // ---- exp + stage P ----
        unsigned short* ps = &Ps[wq][0];
        float rsum[4] = {0.f, 0.f, 0.f, 0.f};
#pragma unroll
        for (int nf = 0; nf < 4; ++nf) {
            const int jl = nf * 16 + lc;
#pragma unroll
            for (int r = 0; r < 4; ++r) {
                const int qr = rg * 4 + r;
                const float p = __expf(sv[nf][r] - mrun[r]);
                rsum[r] += p;
                ps[qr * 64 + (((jl >> 3) ^ (qr & 7)) << 3) + (jl & 7)] = f2bf(p);
            }
        }
#pragma unroll
        for (int r = 0; r < 4; ++r) {
            float rs = rsum[r];
            rs += __shfl_xor(rs, 1);
            rs += __shfl_xor(rs, 2);
            rs += __shfl_xor(rs, 4);
            rs += __shfl_xor(rs, 8);
            lrun[r] = lrun[r] * ef[r] + rs;
        }
        // skip O-rescale when no lane saw a new max (T13-lite)
        const int need_rescale = (ef[0] < 1.f) | (ef[1] < 1.f) | (ef[2] < 1.f) | (ef[3] < 1.f);
        if (__any(need_rescale)) {
#pragma unroll
            for (int nf = 0; nf < 4; ++nf)
#pragma unroll
                for (int r = 0; r < 4; ++r) Oacc[nf][r] *= ef[r];
        }

        // ---- PV ----
        {
            const int c7 = lc & 7;
            const bf16x8 pf0 = *(const bf16x8*)&ps[lc * 64 + ((rg ^ c7) << 3)];
            const bf16x8 pf1 = *(const bf16x8*)&ps[lc * 64 + (((4 + rg) ^ c7) << 3)];
            __builtin_amdgcn_s_setprio(1);
#pragma unroll
            for (int nf = 0; nf < 4; ++nf) {
                const int d = nf * 16 + lc;
                const int d7 = d & 7;
                const bf16x8 vf0 = *(const bf16x8*)&Vt[d * 64 + ((rg ^ d7) << 3)];
                const bf16x8 vf1 = *(const bf16x8*)&Vt[d * 64 + (((4 + rg) ^ d7) << 3)];
                Oacc[nf] = __builtin_amdgcn_mfma_f32_16x16x32_bf16(pf0, vf0, Oacc[nf], 0, 0, 0);
                Oacc[nf] = __builtin_amdgcn_mfma_f32_16x16x32_bf16(pf1, vf1, Oacc[nf], 0, 0, 0);
            }
            __builtin_amdgcn_s_setprio(0);
        }
    }

    // ---- epilogue ----
    float inv[4];
#pragma unroll
    for (int r = 0; r < 4; ++r) inv[r] = 1.0f / lrun[r];
#pragma unroll
    for (int nf = 0; nf < 4; ++nf) {
        const int d = nf * 16 + lc;
#pragma unroll
        for (int r = 0; r < 4; ++r) {
            const int iq = i0 + wq * 16 + rg * 4 + r;
            avb[((size_t)iq * 4 + b) * 1024 + nb + d] = f2bf(Oacc[nf][r] * inv[r]);
        }
    }
}

// ---------------- residual add + layernorm ----------------
__global__ __launch_bounds__(256) void add_ln_kernel(const float* __restrict__ a,
                                                     const float* __restrict__ b,
                                                     const float* __restrict__ w,
                                                     const float* __restrict__ bias,
                                                     float* __restrict__ out,
                                                     unsigned short* __restrict__ out_bf) {
    const int row = blockIdx.x;
    const int t = threadIdx.x;
    __shared__ float xs[DM];
    __shared__ float red[256];

    const float* ar = a + (size_t)row * DM;
    const float* br = b + (size_t)row * DM;

    float lsum = 0.f;
#pragma unroll
    for (int c = t; c < DM; c += 256) {
        float v = ar[c] + br[c];
        xs[c] = v;
        lsum += v;
    }
    red[t] = lsum;
    __syncthreads();
    for (int off = 128; off > 0; off >>= 1) {
        if (t < off) red[t] += red[t + off];
        __syncthreads();
    }
    const float mu = red[0] * (1.0f / DM);
    __syncthreads();

    float lvar = 0.f;
#pragma unroll
    for (int c = t; c < DM; c += 256) {
        float dv = xs[c] - mu;
        lvar += dv * dv;
    }
    red[t] = lvar;
    __syncthreads();
    for (int off = 128; off > 0; off >>= 1) {
        if (t < off) red[t] += red[t + off];
        __syncthreads();
    }
    const float rstd = rsqrtf(red[0] * (1.0f / DM) + LN_EPS);
    __syncthreads();

    float* orow = out + (size_t)row * DM;
#pragma unroll
    for (int c = t; c < DM; c += 256) {
        float v = (xs[c] - mu) * rstd * w[c] + bias[c];
        orow[c] = v;
        if (out_bf) out_bf[(size_t)row * DM + c] = f2bf(v);
    }
}

extern "C" void kernel_launch(void* const* d_in, const int* in_sizes, int n_in,
                              void* d_out, int out_size, void* d_ws, size_t ws_size,
                              hipStream_t stream) {
    const float* dec_inp  = (const float*)d_in[0];
    const float* r        = (const float*)d_in[1];
    const float* r_w_bias = (const float*)d_in[2];
    const float* r_r_bias = (const float*)d_in[3];
    const float* mems     = (const float*)d_in[4];
    const float* qkv_w    = (const float*)d_in[6];
    const float* r_w      = (const float*)d_in[7];
    const float* o_w      = (const float*)d_in[8];
    const float* ln1_w    = (const float*)d_in[9];
    const float* ln1_b    = (const float*)d_in[10];
    const float* ln2_w    = (const float*)d_in[11];
    const float* ln2_b    = (const float*)d_in[12];
    const float* ff_w1    = (const float*)d_in[13];
    const float* ff_b1    = (const float*)d_in[14];
    const float* ff_w2    = (const float*)d_in[15];
    const float* ff_b2    = (const float*)d_in[16];
    float* out = (float*)d_out;
    char* ws = (char*)d_ws;

    unsigned short* catb  = (unsigned short*)(ws + OFF_CATB);
    unsigned short* vtg   = (unsigned short*)(ws + OFF_VTG);
    unsigned short* whb   = (unsigned short*)(ws + OFF_WHB);
    unsigned short* rb    = (unsigned short*)(ws + OFF_RB);
    unsigned short* rhkb  = (unsigned short*)(ws + OFF_RHKB);
    unsigned short* avb   = (unsigned short*)(ws + OFF_AVB);
    float*          tmp   = (float*)(ws + OFF_TMP);
    float*          ln1f  = (float*)(ws + OFF_LN1F);
    unsigned short* ln1b  = (unsigned short*)(ws + OFF_LN1B);
    unsigned short* ffhb  = (unsigned short*)(ws + OFF_FFHB);
    unsigned short* qkvwT = (unsigned short*)(ws + OFF_QKVWT);
    unsigned short* rwT   = (unsigned short*)(ws + OFF_RWT);
    unsigned short* owT   = (unsigned short*)(ws + OFF_OWT);
    unsigned short* ffw1T = (unsigned short*)(ws + OFF_FFW1T);
    unsigned short* ffw2T = (unsigned short*)(ws + OFF_FFW2T);
    float*          bk    = (float*)(ws + OFF_BK);
    float*          brr   = (float*)(ws + OFF_BR);

    // casts & fused weight transposes
    cast_cat<<<dim3(4096), 256, 0, stream>>>(mems, dec_inp, catb);
    cast_f32_bf16<<<dim3(1024), 256, 0, stream>>>(r, rb);
    transpose_cast_all<<<dim3(13312), 256, 0, stream>>>(
        qkv_w, r_w, o_w, ff_w1, ff_w2, qkvwT, rwT, owT, ffw1T, ffw2T);

    // projections
    gemm_bf16<<<dim3(24, 64), 256, 0, stream>>>(catb, qkvwT, nullptr, whb,
                                                KLEN * BSZ, 3 * NHD, DM, 4);
    gemm_bf16<<<dim3(8, 16), 256, 0, stream>>>(rb, rwT, nullptr, rhkb,
                                               KLEN, NHD, DM, 4);

    // attention precomputes (catb dead now; vtg reuses it)
    vtrans<<<dim3(32, 64), 256, 0, stream>>>(whb, vtg);
    bias_kernel<<<dim3(640), 256, 0, stream>>>(whb, rhkb, r_w_bias, r_r_bias, bk, brr);

    // MFMA flash attention: 512 blocks x 512 threads, fully co-resident
    flash_attn_mfma<<<dim3(512), 512, 0, stream>>>(
        whb, rhkb, vtg, bk, brr, avb);

    // output projection + LN + FFN + LN
    gemm_bf16<<<dim3(8, 32), 256, 0, stream>>>(avb, owT, nullptr, tmp,
                                               QLEN * BSZ, DM, NHD, 0);
    add_ln_kernel<<<dim3(QLEN * BSZ), 256, 0, stream>>>(
        dec_inp, tmp, ln1_w, ln1_b, ln1f, ln1b);
    gemm_bf16<<<dim3(32, 32), 256, 0, stream>>>(ln1b, ffw1T, ff_b1, ffhb,
                                                QLEN * BSZ, DI, DM, 1 | 2 | 4);
    gemm_bf16<<<dim3(8, 32), 256, 0, stream>>>(ffhb, ffw2T, ff_b2, tmp,
                                               QLEN * BSZ, DM, DI, 1);
    add_ln_kernel<<<dim3(QLEN * BSZ), 256, 0, stream>>>(
        ln1f, tmp, ln2_w, ln2_b, out, nullptr);
}

// Round 9
// 421.687 us; speedup vs baseline: 1.3181x; 1.0544x over previous
//
#include <hip/hip_runtime.h>
#include <hip/hip_bf16.h>
#include <math.h>

#define QLEN 1024
#define MLEN 1024
#define BSZ 4
#define KLEN 2048
#define NH 16
#define DH 64
#define DM 1024
#define DI 4096
#define NHD 1024
#define LN_EPS 1e-5f

typedef short bf16x8 __attribute__((ext_vector_type(8)));
typedef float f32x4 __attribute__((ext_vector_type(4)));
typedef unsigned int uint4v __attribute__((ext_vector_type(4)));

__device__ __forceinline__ float bf2f(unsigned short u) {
    union { unsigned u32; float f; } x; x.u32 = ((unsigned)u) << 16; return x.f;
}
__device__ __forceinline__ unsigned short f2bf(float f) {
    __hip_bfloat16 h = __float2bfloat16(f);
    return *(unsigned short*)&h;
}

// ---------------- workspace layout (BYTE offsets) ----------------
static const size_t OFF_CATB  = 0;           //  cat bf16 (dead after qkv gemm)
static const size_t OFF_VTG   = 0;           //  Vt_g bf16 [64 bn][64 d][2048 keys] (reuses CATB)
static const size_t OFF_WHB   = 16777216;    //  w_heads bf16 [8192][3072]
static const size_t OFF_RB    = 67108864;    //  r bf16 [2048][1024]
static const size_t OFF_RHKB  = 71303168;    //  r_head_k bf16 [2048][1024]
static const size_t OFF_AVB   = 75497472;    //  attn_vec bf16 [4096][1024]
static const size_t OFF_TMP   = 83886080;    //  tmp fp32 [4096][1024]
static const size_t OFF_LN1F  = 100663296;   //  ln1 fp32
static const size_t OFF_LN1B  = 117440512;   //  ln1 bf16
static const size_t OFF_FFHB  = 125829120;   //  ff_hid bf16 [4096][4096]
static const size_t OFF_QKVWT = 159383552;   //  qkv_w^T bf16 [3072][1024]
static const size_t OFF_RWT   = 165675008;   //  r_w^T bf16
static const size_t OFF_OWT   = 167772160;   //  o_w^T bf16
static const size_t OFF_FFW1T = 169869312;   //  ff_w1^T bf16
static const size_t OFF_FFW2T = 178257920;   //  ff_w2^T bf16

// ---------------- casts ----------------
__global__ __launch_bounds__(256) void cast_cat(const float* __restrict__ mems,
                                                const float* __restrict__ dec,
                                                unsigned short* __restrict__ out) {
    size_t i8 = ((size_t)blockIdx.x * 256 + threadIdx.x) * 8;
    const size_t half = (size_t)MLEN * BSZ * DM;
    const float* src = (i8 < half) ? (mems + i8) : (dec + (i8 - half));
    float4 v0 = *(const float4*)src;
    float4 v1 = *(const float4*)(src + 4);
    ushort4 o0 = {f2bf(v0.x), f2bf(v0.y), f2bf(v0.z), f2bf(v0.w)};
    ushort4 o1 = {f2bf(v1.x), f2bf(v1.y), f2bf(v1.z), f2bf(v1.w)};
    *(ushort4*)&out[i8] = o0;
    *(ushort4*)&out[i8 + 4] = o1;
}

__global__ __launch_bounds__(256) void cast_f32_bf16(const float* __restrict__ in,
                                                     unsigned short* __restrict__ out) {
    size_t i8 = ((size_t)blockIdx.x * 256 + threadIdx.x) * 8;
    float4 v0 = *(const float4*)(in + i8);
    float4 v1 = *(const float4*)(in + i8 + 4);
    ushort4 o0 = {f2bf(v0.x), f2bf(v0.y), f2bf(v0.z), f2bf(v0.w)};
    ushort4 o1 = {f2bf(v1.x), f2bf(v1.y), f2bf(v1.z), f2bf(v1.w)};
    *(ushort4*)&out[i8] = o0;
    *(ushort4*)&out[i8 + 4] = o1;
}

// all 5 weight transposes fused: [K][N] fp32 -> [N][K] bf16
__global__ __launch_bounds__(256) void transpose_cast_all(
        const float* __restrict__ qkv_w, const float* __restrict__ r_w,
        const float* __restrict__ o_w,  const float* __restrict__ ff_w1,
        const float* __restrict__ ff_w2,
        unsigned short* __restrict__ qkvwT, unsigned short* __restrict__ rwT,
        unsigned short* __restrict__ owT, unsigned short* __restrict__ ffw1T,
        unsigned short* __restrict__ ffw2T) {
    __shared__ float tile[32][33];
    const int bid = blockIdx.x;
    const float* in; unsigned short* out; int K, N, nx, lid;
    if (bid < 3072)      { in = qkv_w; out = qkvwT; K = 1024; N = 3072; nx = 96;  lid = bid; }
    else if (bid < 4096) { in = r_w;   out = rwT;   K = 1024; N = 1024; nx = 32;  lid = bid - 3072; }
    else if (bid < 5120) { in = o_w;   out = owT;   K = 1024; N = 1024; nx = 32;  lid = bid - 4096; }
    else if (bid < 9216) { in = ff_w1; out = ffw1T; K = 1024; N = 4096; nx = 128; lid = bid - 5120; }
    else                 { in = ff_w2; out = ffw2T; K = 4096; N = 1024; nx = 32;  lid = bid - 9216; }
    const int n0 = (lid % nx) * 32;
    const int k0 = (lid / nx) * 32;
    const int t = threadIdx.x;
    const int r = t >> 3;
    const int c0 = (t & 7) << 2;
    float4 v = *(const float4*)&in[(size_t)(k0 + r) * N + n0 + c0];
    tile[r][c0 + 0] = v.x; tile[r][c0 + 1] = v.y;
    tile[r][c0 + 2] = v.z; tile[r][c0 + 3] = v.w;
    __syncthreads();
    ushort4 o = {f2bf(tile[c0 + 0][r]), f2bf(tile[c0 + 1][r]),
                 f2bf(tile[c0 + 2][r]), f2bf(tile[c0 + 3][r])};
    *(ushort4*)&out[(size_t)(n0 + r) * K + k0 + c0] = o;
}

// ---------------- bf16 MFMA GEMM (proven: reg-staged dbuf + XOR swizzle) ------
__global__ __launch_bounds__(256) void gemm_bf16(const unsigned short* __restrict__ A,
                                                 const unsigned short* __restrict__ Bt,
                                                 const float* __restrict__ bias,
                                                 void* __restrict__ C,
                                                 int M, int N, int K, int flags) {
    __shared__ __align__(16) unsigned short As[128 * 64];
    __shared__ __align__(16) unsigned short Bs[128 * 64];

    const int tid = threadIdx.x;
    const int w = tid >> 6, l = tid & 63;
    const int wr = w >> 1, wc = w & 1;
    const int row0 = blockIdx.y * 128;
    const int col0 = blockIdx.x * 128;

    f32x4 acc[4][4] = {};

    uint4v ra[4], rb[4];
    {
#pragma unroll
        for (int q = 0; q < 4; ++q) {
            int f = q * 256 + tid, r = f >> 3, c = f & 7;
            ra[q] = *(const uint4v*)&A[(size_t)(row0 + r) * K + c * 8];
            rb[q] = *(const uint4v*)&Bt[(size_t)(col0 + r) * K + c * 8];
        }
    }

    const int nt = K >> 6;
    for (int kt = 0; kt < nt; ++kt) {
        __syncthreads();
#pragma unroll
        for (int q = 0; q < 4; ++q) {
            int f = q * 256 + tid, r = f >> 3, c = f & 7;
            int sw = (c ^ (r & 7)) << 3;
            *(uint4v*)&As[r * 64 + sw] = ra[q];
            *(uint4v*)&Bs[r * 64 + sw] = rb[q];
        }
        __syncthreads();
        if (kt + 1 < nt) {
            const int k0 = (kt + 1) << 6;
#pragma unroll
            for (int q = 0; q < 4; ++q) {
                int f = q * 256 + tid, r = f >> 3, c = f & 7;
                ra[q] = *(const uint4v*)&A[(size_t)(row0 + r) * K + k0 + c * 8];
                rb[q] = *(const uint4v*)&Bt[(size_t)(col0 + r) * K + k0 + c * 8];
            }
        }
#pragma unroll
        for (int ks = 0; ks < 2; ++ks) {
            bf16x8 a[4], bfr[4];
#pragma unroll
            for (int m = 0; m < 4; ++m) {
                int arow = wr * 64 + m * 16 + (l & 15);
                int chunk = (ks * 4 + (l >> 4)) ^ (arow & 7);
                a[m] = *(const bf16x8*)&As[arow * 64 + chunk * 8];
            }
#pragma unroll
            for (int n = 0; n < 4; ++n) {
                int brow = wc * 64 + n * 16 + (l & 15);
                int chunk = (ks * 4 + (l >> 4)) ^ (brow & 7);
                bfr[n] = *(const bf16x8*)&Bs[brow * 64 + chunk * 8];
            }
#pragma unroll
            for (int m = 0; m < 4; ++m)
#pragma unroll
                for (int n = 0; n < 4; ++n)
                    acc[m][n] = __builtin_amdgcn_mfma_f32_16x16x32_bf16(a[m], bfr[n], acc[m][n], 0, 0, 0);
        }
    }

#pragma unroll
    for (int n = 0; n < 4; ++n) {
        const int ccol = col0 + wc * 64 + n * 16 + (l & 15);
        const float bv = (flags & 1) ? bias[ccol] : 0.0f;
#pragma unroll
        for (int m = 0; m < 4; ++m) {
            const int crow0 = row0 + wr * 64 + m * 16 + ((l >> 4) << 2);
#pragma unroll
            for (int reg = 0; reg < 4; ++reg) {
                float v = acc[m][n][reg] + bv;
                if (flags & 2) v = fmaxf(v, 0.0f);
                if (flags & 4)
                    ((unsigned short*)C)[(size_t)(crow0 + reg) * N + ccol] = f2bf(v);
                else
                    ((float*)C)[(size_t)(crow0 + reg) * N + ccol] = v;
            }
        }
    }
}

// ---------------- V transpose to global: Vt_g[bn][d][key] ----------------
__global__ __launch_bounds__(256) void vtrans(const unsigned short* __restrict__ whb,
                                              unsigned short* __restrict__ vtg) {
    __shared__ unsigned short tile[64][72];
    const int bn = blockIdx.y;
    const int b = bn >> 4, n = bn & 15, nb = n * 64;
    const int jt0 = blockIdx.x * 64;
    const int tid = threadIdx.x;
#pragma unroll
    for (int g = 0; g < 2; ++g) {
        int f = g * 256 + tid;
        int key = f >> 3, c = f & 7;
        uint4v v = *(const uint4v*)&whb[((size_t)(jt0 + key) * 4 + b) * 3072 + 2048 + nb + c * 8];
        *(uint4v*)&tile[key][c * 8] = v;
    }
    __syncthreads();
#pragma unroll
    for (int g = 0; g < 2; ++g) {
        int f = g * 256 + tid;
        int d = f >> 3, ck = f & 7;
        unsigned short tmp[8];
#pragma unroll
        for (int e = 0; e < 8; ++e) tmp[e] = tile[ck * 8 + e][d];
        *(uint4v*)&vtg[(size_t)bn * 131072 + (size_t)d * 2048 + jt0 + ck * 8] = *(uint4v*)tmp;
    }
}

// ---------------- MFMA flash attention: swapped-operand (S^T), QBLK=128, 8 waves ------
// S^T = mfma(K_frag, Qac_frag): lane (rg,lc) holds col q=lc, keys kk = nf*16+rg*4+r.
// Biases folded into operands: qac=(Q+wb)/8, qbd=(Q+rb)/8.
// BD band via per-wave LDS scratch [q=16][w=80]; P overlays it as [q][64k] swizzled.
__global__ __launch_bounds__(512) void flash_attn_mfma(const unsigned short* __restrict__ whb,
                                                       const unsigned short* __restrict__ rhkb,
                                                       const unsigned short* __restrict__ vtg,
                                                       const float* __restrict__ r_w_bias,
                                                       const float* __restrict__ r_r_bias,
                                                       unsigned short* __restrict__ avb) {
    const int bid = blockIdx.x;
    const int bn = bid >> 3;
    const int z = bid & 7;
    const int bx = (z & 1) ? (z >> 1) : 7 - (z >> 1);   // pair long+short per CU
    const int b = bn >> 4, n = bn & 15, nb = n * 64;
    const int i0 = bx << 7;
    const int tid = threadIdx.x;
    const int wq = tid >> 6;
    const int lane = tid & 63;
    const int rg = lane >> 4;
    const int lc = lane & 15;
    const int m7 = lc & 7;

    __shared__ __align__(16) unsigned short Ks[4096];     // [key][64d] swizzled (8 KB)
    __shared__ __align__(16) unsigned short Rs[16384];    // 4 circular slots [64][64d] (32 KB)
    __shared__ __align__(16) unsigned short Vt[4096];     // [d][64key] swizzled (8 KB)
    __shared__ __align__(16) unsigned short SCR[8][1280]; // per-wave [16 q][80] BD band / P (20 KB)

    // Q fragments with biases folded + 1/8 prescale (B-operands)
    bf16x8 qac0, qac1, qbd0, qbd1;
    {
        const int qrow = MLEN + i0 + wq * 16 + lc;
        const unsigned short* qp = whb + ((size_t)qrow * 4 + b) * 3072 + nb + rg * 8;
        bf16x8 q0 = *(const bf16x8*)(qp);
        bf16x8 q1 = *(const bf16x8*)(qp + 32);
        const float* wbp = r_w_bias + nb + rg * 8;
        const float* rbp = r_r_bias + nb + rg * 8;
#pragma unroll
        for (int e = 0; e < 8; ++e) {
            const float v0 = bf2f((unsigned short)q0[e]);
            const float v1 = bf2f((unsigned short)q1[e]);
            qac0[e] = (short)f2bf((v0 + wbp[e]) * 0.125f);
            qbd0[e] = (short)f2bf((v0 + rbp[e]) * 0.125f);
            qac1[e] = (short)f2bf((v1 + wbp[32 + e]) * 0.125f);
            qbd1[e] = (short)f2bf((v1 + rbp[32 + e]) * 0.125f);
        }
    }

    f32x4 Oacc[4] = {};
    float mrun = -INFINITY, lrun = 0.f;

    const int ntiles = 2 * bx + 18;
    const int wbase_off = 112 - 16 * wq;

    const int srow = tid >> 3;
    const int sc = tid & 7;
    unsigned short* scr = &SCR[wq][0];

    // ---- prologue: prefetch tile 0 ----
    uint4v pk, pv, pr3[3];
    {
        pk = *(const uint4v*)&whb[((size_t)srow * 4 + b) * 3072 + 1024 + nb + sc * 8];
        pv = *(const uint4v*)&vtg[(size_t)bn * 131072 + (size_t)srow * 2048 + sc * 8];
        const int relbase0 = 896 - i0;
#pragma unroll
        for (int p = 0; p < 3; ++p) {
            const int a = relbase0 + p * 64 + srow;
            pr3[p] = *(const uint4v*)&rhkb[(size_t)a * 1024 + nb + sc * 8];
        }
    }

    for (int kt = 0; kt < ntiles; ++kt) {
        const int jt0 = kt << 6;
        const int relbase = jt0 - i0 + 896;
        __syncthreads();

        // ---- write prefetched regs -> LDS ----
        *(uint4v*)&Ks[srow * 64 + ((sc ^ (srow & 7)) << 3)] = pk;
        *(uint4v*)&Vt[srow * 64 + ((sc ^ (srow & 7)) << 3)] = pv;
        if (kt == 0) {
#pragma unroll
            for (int p = 0; p < 3; ++p) {
                const int a = relbase + p * 64 + srow;
                const int dst = ((a >> 6) & 3) * 4096 + (a & 63) * 64 + ((sc ^ (a & 7)) << 3);
                *(uint4v*)&Rs[dst] = pr3[p];
            }
        } else {
            const int a = relbase + 128 + srow;
            const int dst = ((a >> 6) & 3) * 4096 + (a & 63) * 64 + ((sc ^ (a & 7)) << 3);
            *(uint4v*)&Rs[dst] = pr3[0];
        }
        // ---- issue next-tile prefetch into regs ----
        if (kt + 1 < ntiles) {
            const int jn = jt0 + 64;
            pk = *(const uint4v*)&whb[((size_t)(jn + srow) * 4 + b) * 3072 + 1024 + nb + sc * 8];
            pv = *(const uint4v*)&vtg[(size_t)bn * 131072 + (size_t)srow * 2048 + jn + sc * 8];
            int a = relbase + 192 + srow;
            if (a > 2047) a = 2047;
            pr3[0] = *(const uint4v*)&rhkb[(size_t)a * 1024 + nb + sc * 8];
        }
        __syncthreads();

        // ---- AC^T = mfma(K, Qac): lane holds q=lc, keys nf*16+rg*4+r ----
        f32x4 S[4];
        __builtin_amdgcn_s_setprio(1);
#pragma unroll
        for (int nf = 0; nf < 4; ++nf) {
            const int row = nf * 16 + lc;
            const bf16x8 kf0 = *(const bf16x8*)&Ks[row * 64 + ((rg ^ m7) << 3)];
            const bf16x8 kf1 = *(const bf16x8*)&Ks[row * 64 + (((4 + rg) ^ m7) << 3)];
            f32x4 zz = {0.f, 0.f, 0.f, 0.f};
            zz = __builtin_amdgcn_mfma_f32_16x16x32_bf16(kf0, qac0, zz, 0, 0, 0);
            S[nf] = __builtin_amdgcn_mfma_f32_16x16x32_bf16(kf1, qac1, zz, 0, 0, 0);
        }
        __builtin_amdgcn_s_setprio(0);

        // ---- BD^T band = mfma(Rwin, Qbd) -> per-wave scratch [q][80] ----
        const int wbase = relbase + wbase_off;
#pragma unroll
        for (int g = 0; g < 5; ++g) {
            const int a = wbase + g * 16 + lc;
            const int rbase = ((a >> 6) & 3) * 4096 + (a & 63) * 64;
            const bf16x8 rf0 = *(const bf16x8*)&Rs[rbase + ((rg ^ m7) << 3)];
            const bf16x8 rf1 = *(const bf16x8*)&Rs[rbase + (((4 + rg) ^ m7) << 3)];
            f32x4 bd = {0.f, 0.f, 0.f, 0.f};
            bd = __builtin_amdgcn_mfma_f32_16x16x32_bf16(rf0, qbd0, bd, 0, 0, 0);
            bd = __builtin_amdgcn_mfma_f32_16x16x32_bf16(rf1, qbd1, bd, 0, 0, 0);
            ushort4 p4 = {f2bf(bd[0]), f2bf(bd[1]), f2bf(bd[2]), f2bf(bd[3])};
            *(ushort4*)&scr[lc * 80 + g * 16 + rg * 4] = p4;
        }

        // ---- scores: S += band[q][15+kk-lc]; mask; in-lane max ----
        const bool needmask = (wbase + 78 > 2047);
        float tmax = -INFINITY;
#pragma unroll
        for (int nf = 0; nf < 4; ++nf) {
#pragma unroll
            for (int r = 0; r < 4; ++r) {
                const int wb_ = 15 + nf * 16 + rg * 4 + r - lc;
                float s = S[nf][r] + bf2f(scr[lc * 80 + wb_]);
                if (needmask) s = (wbase + wb_ <= 2047) ? s : -INFINITY;
                S[nf][r] = s;
                tmax = fmaxf(tmax, s);
            }
        }

        // ---- online softmax (per-lane q; reduce across 4 rg copies) ----
        tmax = fmaxf(tmax, __shfl_xor(tmax, 16));
        tmax = fmaxf(tmax, __shfl_xor(tmax, 32));
        const float mn = fmaxf(mrun, tmax);
        const float ef = __expf(mrun - mn);
        mrun = mn;
        float rsum = 0.f;
#pragma unroll
        for (int nf = 0; nf < 4; ++nf) {
#pragma unroll
            for (int r = 0; r < 4; ++r) {
                const float p = __expf(S[nf][r] - mn);
                S[nf][r] = p;
                rsum += p;
            }
        }
        rsum += __shfl_xor(rsum, 16);
        rsum += __shfl_xor(rsum, 32);
        lrun = lrun * ef + rsum;
        if (__any(ef < 1.0f)) {
#pragma unroll
            for (int nf = 0; nf < 4; ++nf)
#pragma unroll
                for (int r = 0; r < 4; ++r) Oacc[nf][r] *= ef;
        }

        // ---- stage P into scratch as [q][64k] swizzled (overlays band; same-wave order) ----
#pragma unroll
        for (int nf = 0; nf < 4; ++nf) {
            ushort4 pw = {f2bf(S[nf][0]), f2bf(S[nf][1]), f2bf(S[nf][2]), f2bf(S[nf][3])};
            const int chunk = nf * 2 + (rg >> 1);
            *(ushort4*)&scr[lc * 80 + ((chunk ^ m7) << 3) + ((rg & 1) << 2)] = pw;
        }

        // ---- PV: O^T = mfma(Vt, P) ----
        {
            const bf16x8 pf0 = *(const bf16x8*)&scr[lc * 80 + ((rg ^ m7) << 3)];
            const bf16x8 pf1 = *(const bf16x8*)&scr[lc * 80 + (((4 + rg) ^ m7) << 3)];
            __builtin_amdgcn_s_setprio(1);
#pragma unroll
            for (int nf = 0; nf < 4; ++nf) {
                const int row = nf * 16 + lc;
                const bf16x8 vf0 = *(const bf16x8*)&Vt[row * 64 + ((rg ^ m7) << 3)];
                const bf16x8 vf1 = *(const bf16x8*)&Vt[row * 64 + (((4 + rg) ^ m7) << 3)];
                Oacc[nf] = __builtin_amdgcn_mfma_f32_16x16x32_bf16(vf0, pf0, Oacc[nf], 0, 0, 0);
                Oacc[nf] = __builtin_amdgcn_mfma_f32_16x16x32_bf16(vf1, pf1, Oacc[nf], 0, 0, 0);
            }
            __builtin_amdgcn_s_setprio(0);
        }
    }

    // ---- epilogue: O^T lane holds q=lc, d = nf*16+rg*4+r ----
    const float inv = 1.0f / lrun;
    const int qg = i0 + wq * 16 + lc;
#pragma unroll
    for (int nf = 0; nf < 4; ++nf) {
        ushort4 o = {f2bf(Oacc[nf][0] * inv), f2bf(Oacc[nf][1] * inv),
                     f2bf(Oacc[nf][2] * inv), f2bf(Oacc[nf][3] * inv)};
        *(ushort4*)&avb[((size_t)qg * 4 + b) * 1024 + nb + nf * 16 + rg * 4] = o;
    }
}

// ---------------- residual add + layernorm ----------------
__global__ __launch_bounds__(256) void add_ln_kernel(const float* __restrict__ a,
                                                     const float* __restrict__ b,
                                                     const float* __restrict__ w,
                                                     const float* __restrict__ bias,
                                                     float* __restrict__ out,
                                                     unsigned short* __restrict__ out_bf) {
    const int row = blockIdx.x;
    const int t = threadIdx.x;
    __shared__ float xs[DM];
    __shared__ float red[256];

    const float* ar = a + (size_t)row * DM;
    const float* br = b + (size_t)row * DM;

    float lsum = 0.f;
#pragma unroll
    for (int c = t; c < DM; c += 256) {
        float v = ar[c] + br[c];
        xs[c] = v;
        lsum += v;
    }
    red[t] = lsum;
    __syncthreads();
    for (int off = 128; off > 0; off >>= 1) {
        if (t < off) red[t] += red[t + off];
        __syncthreads();
    }
    const float mu = red[0] * (1.0f / DM);
    __syncthreads();

    float lvar = 0.f;
#pragma unroll
    for (int c = t; c < DM; c += 256) {
        float dv = xs[c] - mu;
        lvar += dv * dv;
    }
    red[t] = lvar;
    __syncthreads();
    for (int off = 128; off > 0; off >>= 1) {
        if (t < off) red[t] += red[t + off];
        __syncthreads();
    }
    const float rstd = rsqrtf(red[0] * (1.0f / DM) + LN_EPS);
    __syncthreads();

    float* orow = out + (size_t)row * DM;
#pragma unroll
    for (int c = t; c < DM; c += 256) {
        float v = (xs[c] - mu) * rstd * w[c] + bias[c];
        orow[c] = v;
        if (out_bf) out_bf[(size_t)row * DM + c] = f2bf(v);
    }
}

extern "C" void kernel_launch(void* const* d_in, const int* in_sizes, int n_in,
                              void* d_out, int out_size, void* d_ws, size_t ws_size,
                              hipStream_t stream) {
    const float* dec_inp  = (const float*)d_in[0];
    const float* r        = (const float*)d_in[1];
    const float* r_w_bias = (const float*)d_in[2];
    const float* r_r_bias = (const float*)d_in[3];
    const float* mems     = (const float*)d_in[4];
    const float* qkv_w    = (const float*)d_in[6];
    const float* r_w      = (const float*)d_in[7];
    const float* o_w      = (const float*)d_in[8];
    const float* ln1_w    = (const float*)d_in[9];
    const float* ln1_b    = (const float*)d_in[10];
    const float* ln2_w    = (const float*)d_in[11];
    const float* ln2_b    = (const float*)d_in[12];
    const float* ff_w1    = (const float*)d_in[13];
    const float* ff_b1    = (const float*)d_in[14];
    const float* ff_w2    = (const float*)d_in[15];
    const float* ff_b2    = (const float*)d_in[16];
    float* out = (float*)d_out;
    char* ws = (char*)d_ws;

    unsigned short* catb  = (unsigned short*)(ws + OFF_CATB);
    unsigned short* vtg   = (unsigned short*)(ws + OFF_VTG);
    unsigned short* whb   = (unsigned short*)(ws + OFF_WHB);
    unsigned short* rb    = (unsigned short*)(ws + OFF_RB);
    unsigned short* rhkb  = (unsigned short*)(ws + OFF_RHKB);
    unsigned short* avb   = (unsigned short*)(ws + OFF_AVB);
    float*          tmp   = (float*)(ws + OFF_TMP);
    float*          ln1f  = (float*)(ws + OFF_LN1F);
    unsigned short* ln1b  = (unsigned short*)(ws + OFF_LN1B);
    unsigned short* ffhb  = (unsigned short*)(ws + OFF_FFHB);
    unsigned short* qkvwT = (unsigned short*)(ws + OFF_QKVWT);
    unsigned short* rwT   = (unsigned short*)(ws + OFF_RWT);
    unsigned short* owT   = (unsigned short*)(ws + OFF_OWT);
    unsigned short* ffw1T = (unsigned short*)(ws + OFF_FFW1T);
    unsigned short* ffw2T = (unsigned short*)(ws + OFF_FFW2T);

    // casts & fused weight transposes
    cast_cat<<<dim3(4096), 256, 0, stream>>>(mems, dec_inp, catb);
    cast_f32_bf16<<<dim3(1024), 256, 0, stream>>>(r, rb);
    transpose_cast_all<<<dim3(13312), 256, 0, stream>>>(
        qkv_w, r_w, o_w, ff_w1, ff_w2, qkvwT, rwT, owT, ffw1T, ffw2T);

    // projections
    gemm_bf16<<<dim3(24, 64), 256, 0, stream>>>(catb, qkvwT, nullptr, whb,
                                                KLEN * BSZ, 3 * NHD, DM, 4);
    gemm_bf16<<<dim3(8, 16), 256, 0, stream>>>(rb, rwT, nullptr, rhkb,
                                               KLEN, NHD, DM, 4);

    // attention precompute (catb dead now; vtg reuses it)
    vtrans<<<dim3(32, 64), 256, 0, stream>>>(whb, vtg);

    // MFMA flash attention (swapped-operand): 512 blocks x 512 threads
    flash_attn_mfma<<<dim3(512), 512, 0, stream>>>(
        whb, rhkb, vtg, r_w_bias, r_r_bias, avb);

    // output projection + LN + FFN + LN
    gemm_bf16<<<dim3(8, 32), 256, 0, stream>>>(avb, owT, nullptr, tmp,
                                               QLEN * BSZ, DM, NHD, 0);
    add_ln_kernel<<<dim3(QLEN * BSZ), 256, 0, stream>>>(
        dec_inp, tmp, ln1_w, ln1_b, ln1f, ln1b);
    gemm_bf16<<<dim3(32, 32), 256, 0, stream>>>(ln1b, ffw1T, ff_b1, ffhb,
                                                QLEN * BSZ, DI, DM, 1 | 2 | 4);
    gemm_bf16<<<dim3(8, 32), 256, 0, stream>>>(ffhb, ffw2T, ff_b2, tmp,
                                               QLEN * BSZ, DM, DI, 1);
    add_ln_kernel<<<dim3(QLEN * BSZ), 256, 0, stream>>>(
        ln1f, tmp, ln2_w, ln2_b, out, nullptr);
}